// Round 18
// baseline (1054.647 us; speedup 1.0000x reference)
//
#include <hip/hip_runtime.h>

static constexpr int NS = 16384;

typedef __attribute__((ext_vector_type(8))) short bf16x8;   // 8 bf16 / 16B copy unit
typedef __attribute__((ext_vector_type(4))) float f32x4;    // 4 f32 acc

__device__ inline unsigned short bf16_rne(float x) {
  unsigned u = __float_as_uint(x);
  unsigned r = u + 0x7FFF + ((u >> 16) & 1);
  return (unsigned short)(r >> 16);
}

// ------------- weight transpose: w[co][ci][ky][kx] (f32) -> wT[t][ci][co] (f32)
__global__ void k_wtrans(const float* __restrict__ w, float* __restrict__ wT,
                         int CO, int CI_IN, int CI_OUT, int KS) {
  int i = blockIdx.x * 256 + threadIdx.x;
  int tot = KS * KS * CI_OUT * CO;
  if (i >= tot) return;
  int co = i % CO;
  int r = i / CO;
  int ci = r % CI_OUT;
  int t = r / CI_OUT;
  int ky = t / KS, kx = t % KS;
  float v = 0.f;
  if (ci < CI_IN) v = w[((co * CI_IN + ci) * KS + ky) * KS + kx];
  wT[i] = v;
}

// ---- pack 64x64 7x7 weights into MFMA B-frag order, split hi/lo bf16 ----
__global__ void k_wpack(const float* __restrict__ w, unsigned short* __restrict__ wpk) {
  int i = blockIdx.x * 256 + threadIdx.x;
  if (i >= 49 * 64 * 64) return;
  int co = i & 63, r = i >> 6;
  int ci = r & 63, tap = r >> 6;
  float v = w[(co * 64 + ci) * 49 + tap];
  unsigned short hi = bf16_rne(v);
  float hif = __uint_as_float((unsigned)hi << 16);
  unsigned short lo = bf16_rne(v - hif);
  int ks = ci >> 5, k32 = ci & 31;
  int lane = ((k32 >> 3) << 4) | (co & 15);
  int j = ci & 7, nt = co >> 4;
  size_t base = ((size_t)(((tap * 2 + ks) * 4 + nt) * 2) * 64 + lane) * 8 + j;
  wpk[base] = hi;
  wpk[base + 512] = lo;
}

// ---- pack conv5 weights (8,64,7,7) into B-frags: f = (tap*2+ks)*2+sp ----
__global__ void k_wpack5(const float* __restrict__ w5,
                         unsigned short* __restrict__ wpk) {
  int i = blockIdx.x * 256 + threadIdx.x;
  if (i >= 196 * 512) return;
  int j = i & 7, l = (i >> 3) & 63, f = i >> 9;
  int sp = f & 1, r = f >> 1;
  int ks = r & 1, tap = r >> 1;
  int co = l & 15;
  int k32 = ((l >> 4) << 3) + j;
  int ci = ks * 32 + k32;
  float v = (co < 8) ? w5[(co * 64 + ci) * 49 + tap] : 0.f;
  unsigned short hi = bf16_rne(v);
  unsigned short outv;
  if (sp == 0) {
    outv = hi;
  } else {
    float hif = __uint_as_float((unsigned)hi << 16);
    outv = bf16_rne(v - hif);
  }
  wpk[i] = outv;
}

// ---- pack sr1 weights (64,10,9,9) into paired-tap MFMA B-frags, split hi/lo ----
__global__ void k_wpacks(const float* __restrict__ sw1,
                         unsigned short* __restrict__ wpk) {
  int i = blockIdx.x * 256 + threadIdx.x;
  if (i >= 360 * 512) return;
  int j = i & 7, l = (i >> 3) & 63, f = i >> 9;
  int sp = f & 1, nt = (f >> 1) & 3;
  int r3 = f >> 3, p = r3 % 5, ky = r3 / 5;
  int co = nt * 16 + (l & 15);
  int k = ((l >> 4) << 3) + j;
  int kx = 2 * p + (k >> 4);
  int ci = k & 15;
  float v = (ci < 10 && kx < 9) ? sw1[((co * 10 + ci) * 9 + ky) * 9 + kx] : 0.f;
  unsigned short hi = bf16_rne(v);
  unsigned short outv;
  if (sp == 0) {
    outv = hi;
  } else {
    float hif = __uint_as_float((unsigned)hi << 16);
    outv = bf16_rne(v - hif);
  }
  wpk[i] = outv;
}

// ---------------- conv1: 1->64, 7x7, pad3, +bias +PReLU -> f32 NHWC (interior) ------
__global__ __launch_bounds__(128) void k_conv1(
    const float* __restrict__ sino, const float* __restrict__ wT1,
    const float* __restrict__ b1, const float* __restrict__ p1,
    float* __restrict__ out) {
  int b = blockIdx.x >> 7, y = blockIdx.x & 127, x = threadIdx.x;
  float acc[64];
#pragma unroll
  for (int i = 0; i < 64; ++i) acc[i] = 0.f;
#pragma unroll
  for (int ky = 0; ky < 7; ++ky) {
    int yy = y + ky - 3;
#pragma unroll
    for (int kx = 0; kx < 7; ++kx) {
      int xx = x + kx - 3;
      float v = (yy >= 0 && yy < 128 && xx >= 0 && xx < 128)
                    ? sino[(b * 128 + yy) * 128 + xx]
                    : 0.f;
      const float* wr = wT1 + (ky * 7 + kx) * 64;
#pragma unroll
      for (int co = 0; co < 64; ++co) acc[co] += v * wr[co];
    }
  }
  float a = p1[0];
  float* op = out + ((size_t)(b * 134 + y + 3) * 134 + x + 3) * 64;
#pragma unroll
  for (int co = 0; co < 64; ++co) {
    float v = acc[co] + b1[co];
    op[co] = v >= 0.f ? v : a * v;
  }
}

// ---------------- BN stats in f64 (sum, sumsq per channel) ----------------
__global__ __launch_bounds__(256) void k_bnstats(const float* __restrict__ x1p,
                                                 double* __restrict__ bnsum) {
  int c = threadIdx.x & 63, sl = threadIdx.x >> 6;
  double s = 0.0, q = 0.0;
  int base = blockIdx.x * 512 + sl * 128;
  for (int i = 0; i < 128; ++i) {
    int p = base + i;
    int b = p >> 14, y = (p >> 7) & 127, x = p & 127;
    double v = (double)x1p[((size_t)(b * 134 + y + 3) * 134 + x + 3) * 64 + c];
    s += v;
    q += v * v;
  }
  __shared__ double red[2][4][64];
  red[0][sl][c] = s;
  red[1][sl][c] = q;
  __syncthreads();
  if (sl == 0) {
    s = red[0][0][c] + red[0][1][c] + red[0][2][c] + red[0][3][c];
    q = red[1][0][c] + red[1][1][c] + red[1][2][c] + red[1][3][c];
    atomicAdd(&bnsum[c], s);
    atomicAdd(&bnsum[64 + c], q);
  }
}

__global__ void k_bnfinal(const double* __restrict__ bnsum, float* __restrict__ bnsc,
                          const float* __restrict__ g, const float* __restrict__ bb) {
  int c = threadIdx.x;
  if (c >= 64) return;
  double m = bnsum[c] * (1.0 / 65536.0);
  double v = bnsum[64 + c] * (1.0 / 65536.0) - m * m;
  double sc = (double)g[c] * rsqrt(v + 1e-5);
  bnsc[c] = (float)sc;
  bnsc[64 + c] = (float)((double)bb[c] - m * sc);
}

// ---- BN applied to INTERIOR of x1p, emitting hi/lo bf16 planes (halo pre-zeroed) ----
__global__ __launch_bounds__(256) void k_bnapply(
    const float* __restrict__ x1p, const float* __restrict__ bnsc,
    unsigned short* __restrict__ oh, unsigned short* __restrict__ ol) {
  int i = blockIdx.x * 256 + threadIdx.x;  // over 4*128*128*16 float4 groups
  if (i >= 4 * 128 * 128 * 16) return;
  int g = i & 15, p = i >> 4;
  int b = p >> 14, y = (p >> 7) & 127, x = p & 127;
  size_t base = ((size_t)(b * 134 + y + 3) * 134 + x + 3) * 64 + g * 4;
  float4 v = *(const float4*)(x1p + base);
  int c = g * 4;
  v.x = v.x * bnsc[c + 0] + bnsc[64 + c + 0];
  v.y = v.y * bnsc[c + 1] + bnsc[64 + c + 1];
  v.z = v.z * bnsc[c + 2] + bnsc[64 + c + 2];
  v.w = v.w * bnsc[c + 3] + bnsc[64 + c + 3];
  unsigned short h0 = bf16_rne(v.x), h1 = bf16_rne(v.y);
  unsigned short h2 = bf16_rne(v.z), h3 = bf16_rne(v.w);
  unsigned short l0 = bf16_rne(v.x - __uint_as_float((unsigned)h0 << 16));
  unsigned short l1 = bf16_rne(v.y - __uint_as_float((unsigned)h1 << 16));
  unsigned short l2 = bf16_rne(v.z - __uint_as_float((unsigned)h2 << 16));
  unsigned short l3 = bf16_rne(v.w - __uint_as_float((unsigned)h3 << 16));
  *(ushort4*)(oh + base) = make_ushort4(h0, h1, h2, h3);
  *(ushort4*)(ol + base) = make_ushort4(l0, l1, l2, l3);
}

// ======= MFMA conv 64->64 7x7, split-bf16 plane IO, 2-row blocks, 8 waves =======
// grid = B*64 row-pairs (XCD-swizzled: 32 blocks = 64 rows per XCD); block = 512.
// Wave wv: row wv>>2, px-half (wv>>1)&1, co-half wv&1 — per-wave work identical to
// the proven 1-row config, but staging/barriers per output row are ~2x fewer.
// 2-slot ring with slot parity (row r at step ky reads slot (r+ky)&1) — R12 scheme.
__global__ __launch_bounds__(512) void k_convm(
    const unsigned short* __restrict__ inh, const unsigned short* __restrict__ inl,
    const unsigned short* __restrict__ wpk, const float* __restrict__ bias,
    const float* __restrict__ alpha, unsigned short* __restrict__ outh,
    unsigned short* __restrict__ outl) {
  int i0 = (int)((blockIdx.x & 7) * 32 + (blockIdx.x >> 3));
  int b = i0 >> 6, y0 = (i0 & 63) * 2;
  int tid = threadIdx.x, l = tid & 63;
  int wv = tid >> 6;
  int row = wv >> 2;
  int pxb = ((wv >> 1) & 1) * 64;
  int coh = wv & 1;  // co base = coh*32
  int lg = l >> 4, lm = l & 15;

  __shared__ unsigned short hbuf[2][134 * 44];
  __shared__ unsigned short lbuf[2][134 * 44];

  f32x4 acc[4][2];
#pragma unroll
  for (int mt = 0; mt < 4; ++mt)
#pragma unroll
    for (int ntl = 0; ntl < 2; ++ntl) acc[mt][ntl] = (f32x4){0.f, 0.f, 0.f, 0.f};

  for (int ch = 0; ch < 64; ch += 32) {
    auto stage = [&](int k) {  // input row y0+k -> slot k&1 (pure 16B copies)
      const unsigned short* gh = inh + ((size_t)(b * 134 + y0 + k) * 134) * 64 + ch;
      const unsigned short* gl = inl + ((size_t)(b * 134 + y0 + k) * 134) * 64 + ch;
      unsigned short* dh = hbuf[k & 1];
      unsigned short* dl = lbuf[k & 1];
      for (int i = tid; i < 134 * 4; i += 512) {
        int px = i >> 2, q = i & 3;
        bf16x8 vh = *(const bf16x8*)(gh + px * 64 + q * 8);
        bf16x8 vl = *(const bf16x8*)(gl + px * 64 + q * 8);
        *(bf16x8*)&dh[px * 44 + q * 8] = vh;
        *(bf16x8*)&dl[px * 44 + q * 8] = vl;
      }
    };
    stage(0);
    stage(1);
    __syncthreads();
    for (int ky = 0; ky < 7; ++ky) {
      int s = (ky + row) & 1;  // slot holding input row y0+row+ky
      const unsigned short* hb = hbuf[s];
      const unsigned short* lb = lbuf[s];
#pragma unroll
      for (int kx = 0; kx < 7; ++kx) {
        int tap = ky * 7 + kx;
        const unsigned short* wt =
            wpk + (size_t)(tap * 2 + (ch >> 5)) * 8 * 512 + (size_t)l * 8;
        bf16x8 Bh[2], Bl[2];
#pragma unroll
        for (int ntl = 0; ntl < 2; ++ntl) {
          int nt = coh * 2 + ntl;
          Bh[ntl] = *(const bf16x8*)(wt + (nt * 2 + 0) * 512);
          Bl[ntl] = *(const bf16x8*)(wt + (nt * 2 + 1) * 512);
        }
#pragma unroll
        for (int mt = 0; mt < 4; ++mt) {
          int px = pxb + mt * 16 + lm + kx;
          bf16x8 Ah = *(const bf16x8*)&hb[px * 44 + lg * 8];
          bf16x8 Al = *(const bf16x8*)&lb[px * 44 + lg * 8];
#pragma unroll
          for (int ntl = 0; ntl < 2; ++ntl) {
            acc[mt][ntl] = __builtin_amdgcn_mfma_f32_16x16x32_bf16(Ah, Bh[ntl],
                                                                   acc[mt][ntl], 0, 0, 0);
            acc[mt][ntl] = __builtin_amdgcn_mfma_f32_16x16x32_bf16(Ah, Bl[ntl],
                                                                   acc[mt][ntl], 0, 0, 0);
            acc[mt][ntl] = __builtin_amdgcn_mfma_f32_16x16x32_bf16(Al, Bh[ntl],
                                                                   acc[mt][ntl], 0, 0, 0);
          }
        }
      }
      __syncthreads();  // all waves done with slot ky&1 content
      if (ky < 6) {
        stage(ky + 2);  // row y0+ky+2 overwrites slot ky&1
        __syncthreads();
      }
    }
  }
  float a = alpha[0];
#pragma unroll
  for (int mt = 0; mt < 4; ++mt)
#pragma unroll
    for (int ntl = 0; ntl < 2; ++ntl)
#pragma unroll
      for (int r = 0; r < 4; ++r) {
        int px = pxb + mt * 16 + lg * 4 + r;    // D row = (lane>>4)*4 + reg
        int co = coh * 32 + ntl * 16 + lm;      // D col = lane&15
        float v = acc[mt][ntl][r] + bias[co];
        v = v >= 0.f ? v : a * v;
        unsigned short h = bf16_rne(v);
        unsigned short lo = bf16_rne(v - __uint_as_float((unsigned)h << 16));
        size_t idx = ((size_t)(b * 134 + y0 + row + 3) * 134 + px + 3) * 64 + co;
        outh[idx] = h;
        outl[idx] = lo;
      }
}

// ======= MFMA conv5 (64->8) + PReLU + fused GCN lin (8->10), 2-row blocks =======
__global__ __launch_bounds__(512) void k_convm5(
    const unsigned short* __restrict__ inh, const unsigned short* __restrict__ inl,
    const unsigned short* __restrict__ wpk, const float* __restrict__ b5,
    const float* __restrict__ p5, const float* __restrict__ gw,
    float* __restrict__ xl) {
  int i0 = (int)((blockIdx.x & 7) * 32 + (blockIdx.x >> 3));
  int b = i0 >> 6, y0 = (i0 & 63) * 2;
  int tid = threadIdx.x, l = tid & 63;
  int wv = tid >> 6;
  int row = wv >> 2;
  int pxb = (wv & 3) * 32;
  int lg = l >> 4, lm = l & 15;

  __shared__ unsigned short hbuf[2][134 * 44];
  __shared__ unsigned short lbuf[2][134 * 44];
  __shared__ float feat[2][128][9];

  f32x4 acc[2];
  acc[0] = (f32x4){0.f, 0.f, 0.f, 0.f};
  acc[1] = (f32x4){0.f, 0.f, 0.f, 0.f};

  for (int ch = 0; ch < 64; ch += 32) {
    auto stage = [&](int k) {
      const unsigned short* gh = inh + ((size_t)(b * 134 + y0 + k) * 134) * 64 + ch;
      const unsigned short* gl = inl + ((size_t)(b * 134 + y0 + k) * 134) * 64 + ch;
      unsigned short* dh = hbuf[k & 1];
      unsigned short* dl = lbuf[k & 1];
      for (int i = tid; i < 134 * 4; i += 512) {
        int px = i >> 2, q = i & 3;
        bf16x8 vh = *(const bf16x8*)(gh + px * 64 + q * 8);
        bf16x8 vl = *(const bf16x8*)(gl + px * 64 + q * 8);
        *(bf16x8*)&dh[px * 44 + q * 8] = vh;
        *(bf16x8*)&dl[px * 44 + q * 8] = vl;
      }
    };
    stage(0);
    stage(1);
    __syncthreads();
    for (int ky = 0; ky < 7; ++ky) {
      int s = (ky + row) & 1;
      const unsigned short* hb = hbuf[s];
      const unsigned short* lb = lbuf[s];
#pragma unroll
      for (int kx = 0; kx < 7; ++kx) {
        int tap = ky * 7 + kx;
        const unsigned short* wt =
            wpk + (size_t)((tap * 2 + (ch >> 5)) * 2) * 512 + (size_t)l * 8;
        bf16x8 Bh = *(const bf16x8*)(wt);
        bf16x8 Bl = *(const bf16x8*)(wt + 512);
#pragma unroll
        for (int mt = 0; mt < 2; ++mt) {
          int px = pxb + mt * 16 + lm + kx;
          bf16x8 Ah = *(const bf16x8*)&hb[px * 44 + lg * 8];
          bf16x8 Al = *(const bf16x8*)&lb[px * 44 + lg * 8];
          acc[mt] = __builtin_amdgcn_mfma_f32_16x16x32_bf16(Ah, Bh, acc[mt], 0, 0, 0);
          acc[mt] = __builtin_amdgcn_mfma_f32_16x16x32_bf16(Ah, Bl, acc[mt], 0, 0, 0);
          acc[mt] = __builtin_amdgcn_mfma_f32_16x16x32_bf16(Al, Bh, acc[mt], 0, 0, 0);
        }
      }
      __syncthreads();
      if (ky < 6) {
        stage(ky + 2);
        __syncthreads();
      }
    }
  }
  float a = p5[0];
  if (lm < 8) {
#pragma unroll
    for (int mt = 0; mt < 2; ++mt)
#pragma unroll
      for (int r = 0; r < 4; ++r) {
        int px = pxb + mt * 16 + lg * 4 + r;
        float v = acc[mt][r] + b5[lm];
        feat[row][px][lm] = v >= 0.f ? v : a * v;
      }
  }
  __syncthreads();
  if (tid < 256) {
    int rr = tid >> 7, px = tid & 127;
    float o[10];
#pragma unroll
    for (int f = 0; f < 10; ++f) o[f] = 0.f;
#pragma unroll
    for (int c = 0; c < 8; ++c) {
      float fv = feat[rr][px][c];
#pragma unroll
      for (int f = 0; f < 10; ++f) o[f] += fv * gw[c * 10 + f];
    }
    float* op = xl + ((size_t)b * 16384 + (y0 + rr) * 128 + px) * 10;
#pragma unroll
    for (int f = 0; f < 10; ++f) op[f] = o[f];
  }
}

// ======= MFMA sr1: 16->64, 9x9 (kx padded to 10, paired taps -> K=32) =======
__global__ __launch_bounds__(256) void k_convs(
    const float* __restrict__ imgp, const unsigned short* __restrict__ wpk,
    const float* __restrict__ bias, const float* __restrict__ alpha,
    float* __restrict__ out) {
  int i0 = (int)((blockIdx.x & 7) * 64 + (blockIdx.x >> 3));
  int b = i0 >> 7, y = i0 & 127;
  int tid = threadIdx.x, l = tid & 63;
  int wv = tid >> 6, wbase = wv * 32;
  int lg = l >> 4, lm = l & 15;

  __shared__ unsigned short hbuf[2][137 * 20];
  __shared__ unsigned short lbuf[2][137 * 20];

  f32x4 acc[2][4];
#pragma unroll
  for (int mt = 0; mt < 2; ++mt)
#pragma unroll
    for (int nt = 0; nt < 4; ++nt) acc[mt][nt] = (f32x4){0.f, 0.f, 0.f, 0.f};

  auto stage = [&](int ky, int s) {  // input row y+ky -> slot s (px 136 zeroed)
    const float* gin = imgp + ((size_t)(b * 136 + y + ky) * 136) * 16;
    for (int i = tid; i < 137 * 4; i += 256) {
      int px = i >> 2, q = i & 3;
      float4 v = (px < 136) ? *(const float4*)(gin + px * 16 + q * 4)
                            : make_float4(0.f, 0.f, 0.f, 0.f);
      unsigned short h0 = bf16_rne(v.x), h1 = bf16_rne(v.y);
      unsigned short h2 = bf16_rne(v.z), h3 = bf16_rne(v.w);
      unsigned short l0 = bf16_rne(v.x - __uint_as_float((unsigned)h0 << 16));
      unsigned short l1 = bf16_rne(v.y - __uint_as_float((unsigned)h1 << 16));
      unsigned short l2 = bf16_rne(v.z - __uint_as_float((unsigned)h2 << 16));
      unsigned short l3 = bf16_rne(v.w - __uint_as_float((unsigned)h3 << 16));
      *(ushort4*)&hbuf[s][px * 20 + q * 4] = make_ushort4(h0, h1, h2, h3);
      *(ushort4*)&lbuf[s][px * 20 + q * 4] = make_ushort4(l0, l1, l2, l3);
    }
  };
  stage(0, 0);
  __syncthreads();
  for (int ky = 0; ky < 9; ++ky) {
    if (ky < 8) stage(ky + 1, (ky + 1) & 1);
    int s = ky & 1;
#pragma unroll
    for (int p = 0; p < 5; ++p) {
      const unsigned short* wt =
          wpk + ((size_t)(ky * 5 + p) * 8) * 512 + (size_t)l * 8;
      bf16x8 Bh[4], Bl[4];
#pragma unroll
      for (int nt = 0; nt < 4; ++nt) {
        Bh[nt] = *(const bf16x8*)(wt + (nt * 2 + 0) * 512);
        Bl[nt] = *(const bf16x8*)(wt + (nt * 2 + 1) * 512);
      }
#pragma unroll
      for (int mt = 0; mt < 2; ++mt) {
        int px = wbase + mt * 16 + lm + 2 * p + (lg >> 1);
        bf16x8 Ah = *(const bf16x8*)&hbuf[s][px * 20 + (lg & 1) * 8];
        bf16x8 Al = *(const bf16x8*)&lbuf[s][px * 20 + (lg & 1) * 8];
#pragma unroll
        for (int nt = 0; nt < 4; ++nt) {
          acc[mt][nt] =
              __builtin_amdgcn_mfma_f32_16x16x32_bf16(Ah, Bh[nt], acc[mt][nt], 0, 0, 0);
          acc[mt][nt] =
              __builtin_amdgcn_mfma_f32_16x16x32_bf16(Ah, Bl[nt], acc[mt][nt], 0, 0, 0);
          acc[mt][nt] =
              __builtin_amdgcn_mfma_f32_16x16x32_bf16(Al, Bh[nt], acc[mt][nt], 0, 0, 0);
        }
      }
    }
    __syncthreads();
  }
  float a = alpha[0];
#pragma unroll
  for (int mt = 0; mt < 2; ++mt)
#pragma unroll
    for (int nt = 0; nt < 4; ++nt)
#pragma unroll
      for (int r = 0; r < 4; ++r) {
        int px = wbase + mt * 16 + lg * 4 + r;
        int co = nt * 16 + lm;
        float v = acc[mt][nt][r] + bias[co];
        out[((size_t)(b * 128 + y) * 128 + px) * 64 + co] = v >= 0.f ? v : a * v;
      }
}

// --- 2-row conv, NHWC, f32: P=4 (2 rows x 2 px per lane), SGPR weights, CH-split K ---
template <int CIN, int COUT, int KS, int IN_H, int IN_W, int OUT_H, int OUT_W,
          int OUT_OFF, int STR, int CH, int NSPLIT>
__global__ __launch_bounds__(64 * NSPLIT) void k_conv3(
    const float* __restrict__ in, const float* __restrict__ wT,
    const float* __restrict__ bias, const float* __restrict__ alpha,
    float* __restrict__ out) {
  constexpr int C = COUT / NSPLIT;
  int b = blockIdx.x >> 6, y0 = (blockIdx.x & 63) * 2;
  int l = threadIdx.x & 63;
  int cob = __builtin_amdgcn_readfirstlane((int)(threadIdx.x >> 6) * C);
  __shared__ float sbuf[2][IN_W * STR];
  float acc[4][C];
#pragma unroll
  for (int r = 0; r < 4; ++r)
#pragma unroll
    for (int i = 0; i < C; ++i) acc[r][i] = 0.f;

  for (int ch = 0; ch < CIN; ch += CH) {
    auto stage = [&](int k) {
      const float* gin = in + ((size_t)(b * IN_H + y0 + k) * IN_W) * CIN + ch;
      float* dst = sbuf[k & 1];
      constexpr int N4 = IN_W * CH / 4;
      for (int i = threadIdx.x; i < N4; i += 64 * NSPLIT) {
        int xx = i / (CH / 4), c4 = (i - xx * (CH / 4)) * 4;
        float4 v = *(const float4*)(gin + (size_t)xx * CIN + c4);
        *(float4*)(dst + xx * STR + c4) = v;
      }
    };
    stage(0);
    stage(1);
    __syncthreads();
    for (int ky = 0; ky < KS; ++ky) {
      const float* sA = sbuf[ky & 1];
      const float* sB = sbuf[(ky + 1) & 1];
      for (int kx = 0; kx < KS; ++kx) {
        const float* wt = wT + ((size_t)(ky * KS + kx) * CIN + ch) * COUT + cob;
        const float* a0p = sA + (l + kx) * STR;
        const float* a1p = sA + (l + 64 + kx) * STR;
        const float* b0p = sB + (l + kx) * STR;
        const float* b1p = sB + (l + 64 + kx) * STR;
#pragma unroll
        for (int ci = 0; ci < CH; ci += 4) {
          float4 a0 = *(const float4*)(a0p + ci);
          float4 a1 = *(const float4*)(a1p + ci);
          float4 b0 = *(const float4*)(b0p + ci);
          float4 b1 = *(const float4*)(b1p + ci);
#pragma unroll
          for (int c = 0; c < 4; ++c) {
            const float* wr = wt + (size_t)(ci + c) * COUT;
            float va0 = ((const float*)&a0)[c], va1 = ((const float*)&a1)[c];
            float vb0 = ((const float*)&b0)[c], vb1 = ((const float*)&b1)[c];
#pragma unroll
            for (int co = 0; co < C; ++co) {
              float w = wr[co];
              acc[0][co] += va0 * w;
              acc[1][co] += va1 * w;
              acc[2][co] += vb0 * w;
              acc[3][co] += vb1 * w;
            }
          }
        }
      }
      __syncthreads();
      if (ky < KS - 1) {
        stage(ky + 2);
        __syncthreads();
      }
    }
  }
  float a = alpha[0];
#pragma unroll
  for (int r = 0; r < 2; ++r) {
    float* rowp =
        out + (((size_t)(b * OUT_H + y0 + r + OUT_OFF)) * OUT_W + OUT_OFF) * COUT + cob;
#pragma unroll
    for (int p = 0; p < 2; ++p) {
      float* op = rowp + (size_t)(l + p * 64) * COUT;
#pragma unroll
      for (int co = 0; co < C; ++co) {
        float v = acc[r * 2 + p][co] + bias[cob + co];
        op[co] = v >= 0.f ? v : a * v;
      }
    }
  }
}

// ------- single-row conv (kept for sr3: COUT=1), pixel-pair, SGPR weights ----------
template <int CIN, int COUT, int KS, int IN_H, int IN_W, int OUT_H, int OUT_W,
          int OUT_OFF, int STR, int NSPLIT>
__global__ __launch_bounds__(64 * NSPLIT) void k_conv2(
    const float* __restrict__ in, const float* __restrict__ wT,
    const float* __restrict__ bias, const float* __restrict__ alpha,
    float* __restrict__ out) {
  constexpr int C = COUT / NSPLIT;
  int b = blockIdx.x >> 7, y = blockIdx.x & 127;
  int l = threadIdx.x & 63;
  int cob = __builtin_amdgcn_readfirstlane((int)(threadIdx.x >> 6) * C);
  __shared__ float srow[IN_W * STR];
  float acc0[C], acc1[C];
#pragma unroll
  for (int i = 0; i < C; ++i) acc0[i] = acc1[i] = 0.f;

  for (int ky = 0; ky < KS; ++ky) {
    __syncthreads();
    const float* gin = in + (size_t)(b * IN_H + y + ky) * IN_W * CIN;
    constexpr int N4 = IN_W * CIN / 4;
    for (int i = threadIdx.x; i < N4; i += 64 * NSPLIT) {
      float4 v = *(const float4*)(gin + (size_t)i * 4);
      int xx = (i * 4) / CIN, cc = (i * 4) % CIN;
      *(float4*)(srow + xx * STR + cc) = v;
    }
    __syncthreads();
    for (int kx = 0; kx < KS; ++kx) {
      const float* wt = wT + ((size_t)(ky * KS + kx) * CIN) * COUT + cob;
      const float* s0 = srow + (l + kx) * STR;
      const float* s1 = srow + (l + 64 + kx) * STR;
      for (int ci = 0; ci < CIN; ci += 4) {
        float4 a0 = *(const float4*)(s0 + ci);
        float4 a1 = *(const float4*)(s1 + ci);
#pragma unroll
        for (int c = 0; c < 4; ++c) {
          float v0 = ((const float*)&a0)[c];
          float v1 = ((const float*)&a1)[c];
          const float* wr = wt + (size_t)(ci + c) * COUT;
#pragma unroll
          for (int co = 0; co < C; ++co) {
            float w = wr[co];
            acc0[co] += v0 * w;
            acc1[co] += v1 * w;
          }
        }
      }
    }
  }
  float a = alpha[0];
  float* rowp = out + ((size_t)(b * OUT_H + y + OUT_OFF) * OUT_W + OUT_OFF) * COUT + cob;
  float* op0 = rowp + (size_t)l * COUT;
  float* op1 = rowp + (size_t)(l + 64) * COUT;
#pragma unroll
  for (int co = 0; co < C; ++co) {
    float bi = bias[cob + co];
    float v0 = acc0[co] + bi;
    float v1 = acc1[co] + bi;
    op0[co] = v0 >= 0.f ? v0 : a * v0;
    op1[co] = v1 >= 0.f ? v1 : a * v1;
  }
}

// ====== GCN edge pipeline, LDS-privatized ======
template <int HALF>
__global__ __launch_bounds__(1024) void k_degp(
    const int* __restrict__ ei, const float* __restrict__ ew,
    float* __restrict__ pdeg, int* __restrict__ cnt, int* __restrict__ rank, int E) {
  __shared__ float degl[16384];
  for (int i = threadIdx.x; i < 16384; i += 1024) degl[i] = 0.f;
  __syncthreads();
  int chunk = (E + gridDim.x - 1) / gridDim.x;
  int base = blockIdx.x * chunk;
  int end = min(E, base + chunk);
  for (int e = base + (int)threadIdx.x; e < end; e += 1024) {
    int col = ei[E + e];
    float w = ew[e];
    if ((col >> 14) == HALF) atomicAdd(&degl[col & 16383], w);
    if (HALF == 1) {
      int row = ei[e];
      if (row < NS && col >= NS) rank[e] = atomicAdd(&cnt[col - NS], 1);
    }
  }
  __syncthreads();
  float* pd = pdeg + (size_t)blockIdx.x * 16384;
  for (int i = threadIdx.x; i < 16384; i += 1024) pd[i] = degl[i];
}

__global__ void k_dis2(const float* __restrict__ pdegA, const float* __restrict__ pdegB,
                       float* __restrict__ dis, int nb) {
  int n = blockIdx.x * 256 + threadIdx.x;
  if (n >= 2 * NS) return;
  const float* p = (n < NS ? pdegA : pdegB) + (n & 16383);
  float s = 1.0f;
  for (int b = 0; b < nb; ++b) s += p[(size_t)b * 16384];
  dis[n] = rsqrtf(s);
}

__global__ __launch_bounds__(1024) void k_scan(const int* __restrict__ cnt,
                                               int* __restrict__ ptr) {
  __shared__ int ps[1024];
  int tid = threadIdx.x;
  int base = tid * 16;
  int v[16];
  int s = 0;
#pragma unroll
  for (int k = 0; k < 16; ++k) {
    v[k] = s;
    s += cnt[base + k];
  }
  ps[tid] = s;
  __syncthreads();
  for (int off = 1; off < 1024; off <<= 1) {
    int t = (tid >= off) ? ps[tid - off] : 0;
    __syncthreads();
    ps[tid] += t;
    __syncthreads();
  }
  int chunkoff = (tid == 0) ? 0 : ps[tid - 1];
#pragma unroll
  for (int k = 0; k < 16; ++k) ptr[base + k] = chunkoff + v[k];
  if (tid == 1023) ptr[16384] = ps[1023];
}

__global__ void k_bucket2(const int* __restrict__ ei, const float* __restrict__ ew,
                          const float* __restrict__ dis, const int* __restrict__ ptr,
                          const int* __restrict__ rank, int* __restrict__ erow,
                          float* __restrict__ enrm, int E) {
  int e = blockIdx.x * 256 + threadIdx.x;
  if (e >= E) return;
  int row = ei[e], col = ei[E + e];
  if (row >= NS || col < NS) return;
  int cp = col - NS;
  int pos = ptr[cp] + rank[e];
  erow[pos] = row;
  enrm[pos] = dis[row] * ew[e] * dis[col];
}

__global__ __launch_bounds__(256) void k_gather(
    const int* __restrict__ ptr, const int* __restrict__ erow,
    const float* __restrict__ enrm, const float* __restrict__ xl,
    const float* __restrict__ gb, float* __restrict__ imgp) {
  int cp = blockIdx.x * 4 + (threadIdx.x >> 6);
  int l = threadIdx.x & 63;
  int b = l >> 4, f = l & 15;
  bool act = f < 10;
  float acc = 0.f;
  int s = ptr[cp], e1 = ptr[cp + 1];
  for (int e = s; e < e1; ++e) {
    int row = erow[e];
    float nrm = enrm[e];
    if (act) acc += xl[((size_t)b * 16384 + row) * 10 + f] * nrm;
  }
  if (act) {
    int y = cp >> 7, x = cp & 127;
    imgp[((size_t)(b * 136 + y + 4) * 136 + x + 4) * 16 + f] = acc + gb[f];
  }
}

// ---------------- launcher ----------------
extern "C" void kernel_launch(void* const* d_in, const int* in_sizes, int n_in,
                              void* d_out, int out_size, void* d_ws, size_t ws_size,
                              hipStream_t stream) {
  const float* sino = (const float*)d_in[0];
  const int* ei = (const int*)d_in[1];
  const float* ew = (const float*)d_in[2];
  const float* w1 = (const float*)d_in[3];
  const float* w2 = (const float*)d_in[4];
  const float* w3 = (const float*)d_in[5];
  const float* w4 = (const float*)d_in[6];
  const float* w5 = (const float*)d_in[7];
  const float* gw = (const float*)d_in[8];
  const float* sw1 = (const float*)d_in[9];
  const float* sw2 = (const float*)d_in[10];
  const float* sw3 = (const float*)d_in[11];
  const float* b1 = (const float*)d_in[12];
  const float* b2 = (const float*)d_in[13];
  const float* b3 = (const float*)d_in[14];
  const float* b4 = (const float*)d_in[15];
  const float* b5 = (const float*)d_in[16];
  const float* sb1 = (const float*)d_in[17];
  const float* sb2 = (const float*)d_in[18];
  const float* sb3 = (const float*)d_in[19];
  const float* gb = (const float*)d_in[20];
  const float* bng = (const float*)d_in[21];
  const float* bnb = (const float*)d_in[22];
  const float* p1 = (const float*)d_in[23];
  const float* p2 = (const float*)d_in[24];
  const float* p3 = (const float*)d_in[25];
  const float* p4 = (const float*)d_in[26];
  const float* p5 = (const float*)d_in[27];
  const float* sp1 = (const float*)d_in[28];
  const float* sp2 = (const float*)d_in[29];
  const float* sp3 = (const float*)d_in[30];
  const int E = in_sizes[2];

  char* ws = (char*)d_ws;
  size_t off = 0;
  auto alloc = [&](size_t bytes) {
    char* p = ws + off;
    off += (bytes + 255) & ~(size_t)255;
    return p;
  };
  const size_t PL = (size_t)4 * 134 * 134 * 64;  // plane elements
  float* x1p = (float*)alloc(PL * 4);
  unsigned short* xh1 = (unsigned short*)alloc(PL * 2);
  unsigned short* xl1 = (unsigned short*)alloc(PL * 2);
  unsigned short* xh2 = (unsigned short*)alloc(PL * 2);
  unsigned short* xl2 = (unsigned short*)alloc(PL * 2);
  unsigned short* wpk2 = (unsigned short*)alloc(401408 * 2);
  unsigned short* wpk3 = (unsigned short*)alloc(401408 * 2);
  unsigned short* wpk4 = (unsigned short*)alloc(401408 * 2);
  unsigned short* wpk5 = (unsigned short*)alloc(100352 * 2);
  unsigned short* wpks1 = (unsigned short*)alloc(184320 * 2);
  float* wt1 = (float*)alloc(3136 * 4);
  float* wts2 = (float*)alloc(2048 * 4);
  float* wts3 = (float*)alloc(800 * 4);
  double* bnsum = (double*)alloc(128 * 8);
  float* bnsc = (float*)alloc(128 * 4);
  float* xl = (float*)alloc((size_t)4 * 16384 * 10 * 4);
  float* pdegA = (float*)alloc((size_t)128 * 16384 * 4);
  float* pdegB = (float*)alloc((size_t)128 * 16384 * 4);
  float* dis = (float*)alloc(32768 * 4);
  int* cnt = (int*)alloc(16384 * 4);
  int* ptr = (int*)alloc(16385 * 4);
  int* rank = (int*)alloc((size_t)E * 4);
  int* erow = (int*)alloc((size_t)E * 4);
  float* enrm = (float*)alloc((size_t)E * 4);
  float* imgp = (float*)alloc((size_t)4 * 136 * 136 * 16 * 4);
  float* s1 = (float*)alloc((size_t)4 * 128 * 128 * 64 * 4);
  float* s2p = (float*)alloc((size_t)4 * 132 * 132 * 32 * 4);

  // zero plane halos / accumulators (bf16 zero == 0x0000)
  hipMemsetAsync(xh1, 0, PL * 2, stream);
  hipMemsetAsync(xl1, 0, PL * 2, stream);
  hipMemsetAsync(xh2, 0, PL * 2, stream);
  hipMemsetAsync(xl2, 0, PL * 2, stream);
  hipMemsetAsync(bnsum, 0, 128 * 8, stream);
  hipMemsetAsync(cnt, 0, 16384 * 4, stream);
  hipMemsetAsync(imgp, 0, (size_t)4 * 136 * 136 * 16 * 4, stream);
  hipMemsetAsync(s2p, 0, (size_t)4 * 132 * 132 * 32 * 4, stream);

  // weight prep
  k_wpack<<<784, 256, 0, stream>>>(w2, wpk2);
  k_wpack<<<784, 256, 0, stream>>>(w3, wpk3);
  k_wpack<<<784, 256, 0, stream>>>(w4, wpk4);
  k_wpack5<<<392, 256, 0, stream>>>(w5, wpk5);
  k_wpacks<<<720, 256, 0, stream>>>(sw1, wpks1);
  k_wtrans<<<13, 256, 0, stream>>>(w1, wt1, 64, 1, 1, 7);
  k_wtrans<<<8, 256, 0, stream>>>(sw2, wts2, 32, 64, 64, 1);
  k_wtrans<<<4, 256, 0, stream>>>(sw3, wts3, 1, 32, 32, 5);

  k_conv1<<<512, 128, 0, stream>>>(sino, wt1, b1, p1, x1p);
  k_bnstats<<<128, 256, 0, stream>>>(x1p, bnsum);
  k_bnfinal<<<1, 64, 0, stream>>>(bnsum, bnsc, bng, bnb);
  // BN on interior -> hi/lo planes (halo stays zero; ref zero-pads AFTER BN).
  k_bnapply<<<4096, 256, 0, stream>>>(x1p, bnsc, xh1, xl1);

  // MFMA split-bf16 convs: 2-row blocks, 8 waves, XCD-swizzled, plane IO
  k_convm<<<256, 512, 0, stream>>>(xh1, xl1, wpk2, b2, p2, xh2, xl2);
  k_convm<<<256, 512, 0, stream>>>(xh2, xl2, wpk3, b3, p3, xh1, xl1);
  k_convm<<<256, 512, 0, stream>>>(xh1, xl1, wpk4, b4, p4, xh2, xl2);
  // conv5 + GCN lin via MFMA (2-row blocks)
  k_convm5<<<256, 512, 0, stream>>>(xh2, xl2, wpk5, b5, p5, gw, xl);

  // edge pipeline: LDS-privatized deg partials + fused CSR rank
  k_degp<0><<<128, 1024, 0, stream>>>(ei, ew, pdegA, cnt, rank, E);
  k_degp<1><<<128, 1024, 0, stream>>>(ei, ew, pdegB, cnt, rank, E);
  k_dis2<<<128, 256, 0, stream>>>(pdegA, pdegB, dis, 128);
  k_scan<<<1, 1024, 0, stream>>>(cnt, ptr);
  k_bucket2<<<(E + 255) / 256, 256, 0, stream>>>(ei, ew, dis, ptr, rank, erow, enrm, E);
  k_gather<<<4096, 256, 0, stream>>>(ptr, erow, enrm, xl, gb, imgp);

  // sr1 via MFMA paired-tap kernel
  k_convs<<<512, 256, 0, stream>>>(imgp, wpks1, sb1, sp1, s1);
  k_conv3<64, 32, 1, 128, 128, 132, 132, 2, 36, 32, 8>
      <<<256, 512, 0, stream>>>(s1, wts2, sb2, sp2, s2p);
  k_conv2<32, 1, 5, 132, 132, 128, 128, 0, 36, 1>
      <<<512, 64, 0, stream>>>(s2p, wts3, sb3, sp3, (float*)d_out);
}

// Round 19
// 632.722 us; speedup vs baseline: 1.6668x; 1.6668x over previous
//
#include <hip/hip_runtime.h>

static constexpr int NS = 16384;

typedef __attribute__((ext_vector_type(8))) short bf16x8;   // 8 bf16 / 16B copy unit
typedef __attribute__((ext_vector_type(4))) float f32x4;    // 4 f32 acc

__device__ inline unsigned short bf16_rne(float x) {
  unsigned u = __float_as_uint(x);
  unsigned r = u + 0x7FFF + ((u >> 16) & 1);
  return (unsigned short)(r >> 16);
}

// ------------- weight transpose: w[co][ci][ky][kx] (f32) -> wT[t][ci][co] (f32)
__global__ void k_wtrans(const float* __restrict__ w, float* __restrict__ wT,
                         int CO, int CI_IN, int CI_OUT, int KS) {
  int i = blockIdx.x * 256 + threadIdx.x;
  int tot = KS * KS * CI_OUT * CO;
  if (i >= tot) return;
  int co = i % CO;
  int r = i / CO;
  int ci = r % CI_OUT;
  int t = r / CI_OUT;
  int ky = t / KS, kx = t % KS;
  float v = 0.f;
  if (ci < CI_IN) v = w[((co * CI_IN + ci) * KS + ky) * KS + kx];
  wT[i] = v;
}

// ---- pack 64x64 7x7 weights into MFMA B-frag order, split hi/lo bf16 ----
__global__ void k_wpack(const float* __restrict__ w, unsigned short* __restrict__ wpk) {
  int i = blockIdx.x * 256 + threadIdx.x;
  if (i >= 49 * 64 * 64) return;
  int co = i & 63, r = i >> 6;
  int ci = r & 63, tap = r >> 6;
  float v = w[(co * 64 + ci) * 49 + tap];
  unsigned short hi = bf16_rne(v);
  float hif = __uint_as_float((unsigned)hi << 16);
  unsigned short lo = bf16_rne(v - hif);
  int ks = ci >> 5, k32 = ci & 31;
  int lane = ((k32 >> 3) << 4) | (co & 15);
  int j = ci & 7, nt = co >> 4;
  size_t base = ((size_t)(((tap * 2 + ks) * 4 + nt) * 2) * 64 + lane) * 8 + j;
  wpk[base] = hi;
  wpk[base + 512] = lo;
}

// ---- pack conv5 weights (8,64,7,7) into B-frags: f = (tap*2+ks)*2+sp ----
__global__ void k_wpack5(const float* __restrict__ w5,
                         unsigned short* __restrict__ wpk) {
  int i = blockIdx.x * 256 + threadIdx.x;
  if (i >= 196 * 512) return;
  int j = i & 7, l = (i >> 3) & 63, f = i >> 9;
  int sp = f & 1, r = f >> 1;
  int ks = r & 1, tap = r >> 1;
  int co = l & 15;
  int k32 = ((l >> 4) << 3) + j;
  int ci = ks * 32 + k32;
  float v = (co < 8) ? w5[(co * 64 + ci) * 49 + tap] : 0.f;
  unsigned short hi = bf16_rne(v);
  unsigned short outv;
  if (sp == 0) {
    outv = hi;
  } else {
    float hif = __uint_as_float((unsigned)hi << 16);
    outv = bf16_rne(v - hif);
  }
  wpk[i] = outv;
}

// ---- pack sr1 weights (64,10,9,9) into paired-tap MFMA B-frags, split hi/lo ----
__global__ void k_wpacks(const float* __restrict__ sw1,
                         unsigned short* __restrict__ wpk) {
  int i = blockIdx.x * 256 + threadIdx.x;
  if (i >= 360 * 512) return;
  int j = i & 7, l = (i >> 3) & 63, f = i >> 9;
  int sp = f & 1, nt = (f >> 1) & 3;
  int r3 = f >> 3, p = r3 % 5, ky = r3 / 5;
  int co = nt * 16 + (l & 15);
  int k = ((l >> 4) << 3) + j;
  int kx = 2 * p + (k >> 4);
  int ci = k & 15;
  float v = (ci < 10 && kx < 9) ? sw1[((co * 10 + ci) * 9 + ky) * 9 + kx] : 0.f;
  unsigned short hi = bf16_rne(v);
  unsigned short outv;
  if (sp == 0) {
    outv = hi;
  } else {
    float hif = __uint_as_float((unsigned)hi << 16);
    outv = bf16_rne(v - hif);
  }
  wpk[i] = outv;
}

// ---------------- conv1: 1->64, 7x7, pad3, +bias +PReLU -> f32 NHWC (interior) ------
__global__ __launch_bounds__(128) void k_conv1(
    const float* __restrict__ sino, const float* __restrict__ wT1,
    const float* __restrict__ b1, const float* __restrict__ p1,
    float* __restrict__ out) {
  int b = blockIdx.x >> 7, y = blockIdx.x & 127, x = threadIdx.x;
  float acc[64];
#pragma unroll
  for (int i = 0; i < 64; ++i) acc[i] = 0.f;
#pragma unroll
  for (int ky = 0; ky < 7; ++ky) {
    int yy = y + ky - 3;
#pragma unroll
    for (int kx = 0; kx < 7; ++kx) {
      int xx = x + kx - 3;
      float v = (yy >= 0 && yy < 128 && xx >= 0 && xx < 128)
                    ? sino[(b * 128 + yy) * 128 + xx]
                    : 0.f;
      const float* wr = wT1 + (ky * 7 + kx) * 64;
#pragma unroll
      for (int co = 0; co < 64; ++co) acc[co] += v * wr[co];
    }
  }
  float a = p1[0];
  float* op = out + ((size_t)(b * 134 + y + 3) * 134 + x + 3) * 64;
#pragma unroll
  for (int co = 0; co < 64; ++co) {
    float v = acc[co] + b1[co];
    op[co] = v >= 0.f ? v : a * v;
  }
}

// ---------------- BN stats in f64 (sum, sumsq per channel) ----------------
__global__ __launch_bounds__(256) void k_bnstats(const float* __restrict__ x1p,
                                                 double* __restrict__ bnsum) {
  int c = threadIdx.x & 63, sl = threadIdx.x >> 6;
  double s = 0.0, q = 0.0;
  int base = blockIdx.x * 512 + sl * 128;
  for (int i = 0; i < 128; ++i) {
    int p = base + i;
    int b = p >> 14, y = (p >> 7) & 127, x = p & 127;
    double v = (double)x1p[((size_t)(b * 134 + y + 3) * 134 + x + 3) * 64 + c];
    s += v;
    q += v * v;
  }
  __shared__ double red[2][4][64];
  red[0][sl][c] = s;
  red[1][sl][c] = q;
  __syncthreads();
  if (sl == 0) {
    s = red[0][0][c] + red[0][1][c] + red[0][2][c] + red[0][3][c];
    q = red[1][0][c] + red[1][1][c] + red[1][2][c] + red[1][3][c];
    atomicAdd(&bnsum[c], s);
    atomicAdd(&bnsum[64 + c], q);
  }
}

__global__ void k_bnfinal(const double* __restrict__ bnsum, float* __restrict__ bnsc,
                          const float* __restrict__ g, const float* __restrict__ bb) {
  int c = threadIdx.x;
  if (c >= 64) return;
  double m = bnsum[c] * (1.0 / 65536.0);
  double v = bnsum[64 + c] * (1.0 / 65536.0) - m * m;
  double sc = (double)g[c] * rsqrt(v + 1e-5);
  bnsc[c] = (float)sc;
  bnsc[64 + c] = (float)((double)bb[c] - m * sc);
}

// ---- BN applied to INTERIOR of x1p, emitting hi/lo bf16 planes (halo pre-zeroed) ----
__global__ __launch_bounds__(256) void k_bnapply(
    const float* __restrict__ x1p, const float* __restrict__ bnsc,
    unsigned short* __restrict__ oh, unsigned short* __restrict__ ol) {
  int i = blockIdx.x * 256 + threadIdx.x;  // over 4*128*128*16 float4 groups
  if (i >= 4 * 128 * 128 * 16) return;
  int g = i & 15, p = i >> 4;
  int b = p >> 14, y = (p >> 7) & 127, x = p & 127;
  size_t base = ((size_t)(b * 134 + y + 3) * 134 + x + 3) * 64 + g * 4;
  float4 v = *(const float4*)(x1p + base);
  int c = g * 4;
  v.x = v.x * bnsc[c + 0] + bnsc[64 + c + 0];
  v.y = v.y * bnsc[c + 1] + bnsc[64 + c + 1];
  v.z = v.z * bnsc[c + 2] + bnsc[64 + c + 2];
  v.w = v.w * bnsc[c + 3] + bnsc[64 + c + 3];
  unsigned short h0 = bf16_rne(v.x), h1 = bf16_rne(v.y);
  unsigned short h2 = bf16_rne(v.z), h3 = bf16_rne(v.w);
  unsigned short l0 = bf16_rne(v.x - __uint_as_float((unsigned)h0 << 16));
  unsigned short l1 = bf16_rne(v.y - __uint_as_float((unsigned)h1 << 16));
  unsigned short l2 = bf16_rne(v.z - __uint_as_float((unsigned)h2 << 16));
  unsigned short l3 = bf16_rne(v.w - __uint_as_float((unsigned)h3 << 16));
  *(ushort4*)(oh + base) = make_ushort4(h0, h1, h2, h3);
  *(ushort4*)(ol + base) = make_ushort4(l0, l1, l2, l3);
}

// ======= MFMA conv 64->64 7x7, split-bf16 plane IO, co-split waves (R17 proven) =====
// 1-row blocks, 4 waves, stage overlapped with compute (single-barrier pipeline).
// XCD swizzle: 64 consecutive rows per XCD. LDS px stride 44 (conflict-light).
__global__ __launch_bounds__(256) void k_convm(
    const unsigned short* __restrict__ inh, const unsigned short* __restrict__ inl,
    const unsigned short* __restrict__ wpk, const float* __restrict__ bias,
    const float* __restrict__ alpha, unsigned short* __restrict__ outh,
    unsigned short* __restrict__ outl) {
  int i0 = (int)((blockIdx.x & 7) * 64 + (blockIdx.x >> 3));
  int b = i0 >> 7, y = i0 & 127;
  int tid = threadIdx.x, l = tid & 63;
  int wv = tid >> 6;
  int pxb = (wv & 1) * 64;
  int coh = wv >> 1;  // co base = coh*32
  int lg = l >> 4, lm = l & 15;

  __shared__ unsigned short hbuf[2][134 * 44];
  __shared__ unsigned short lbuf[2][134 * 44];

  f32x4 acc[4][2];
#pragma unroll
  for (int mt = 0; mt < 4; ++mt)
#pragma unroll
    for (int ntl = 0; ntl < 2; ++ntl) acc[mt][ntl] = (f32x4){0.f, 0.f, 0.f, 0.f};

  for (int ch = 0; ch < 64; ch += 32) {
    auto stage = [&](int ky, int s) {  // pure copy: 2x ushort8 per iter
      const unsigned short* gh = inh + ((size_t)(b * 134 + y + ky) * 134) * 64 + ch;
      const unsigned short* gl = inl + ((size_t)(b * 134 + y + ky) * 134) * 64 + ch;
      for (int i = tid; i < 134 * 4; i += 256) {
        int px = i >> 2, q = i & 3;
        bf16x8 vh = *(const bf16x8*)(gh + px * 64 + q * 8);
        bf16x8 vl = *(const bf16x8*)(gl + px * 64 + q * 8);
        *(bf16x8*)&hbuf[s][px * 44 + q * 8] = vh;
        *(bf16x8*)&lbuf[s][px * 44 + q * 8] = vl;
      }
    };
    stage(0, 0);
    __syncthreads();
    for (int ky = 0; ky < 7; ++ky) {
      if (ky < 6) stage(ky + 1, (ky + 1) & 1);  // overlaps with compute below
      int s = ky & 1;
#pragma unroll
      for (int kx = 0; kx < 7; ++kx) {
        int tap = ky * 7 + kx;
        const unsigned short* wt =
            wpk + (size_t)(tap * 2 + (ch >> 5)) * 8 * 512 + (size_t)l * 8;
        bf16x8 Bh[2], Bl[2];
#pragma unroll
        for (int ntl = 0; ntl < 2; ++ntl) {
          int nt = coh * 2 + ntl;
          Bh[ntl] = *(const bf16x8*)(wt + (nt * 2 + 0) * 512);
          Bl[ntl] = *(const bf16x8*)(wt + (nt * 2 + 1) * 512);
        }
#pragma unroll
        for (int mt = 0; mt < 4; ++mt) {
          int px = pxb + mt * 16 + lm + kx;
          bf16x8 Ah = *(const bf16x8*)&hbuf[s][px * 44 + lg * 8];
          bf16x8 Al = *(const bf16x8*)&lbuf[s][px * 44 + lg * 8];
#pragma unroll
          for (int ntl = 0; ntl < 2; ++ntl) {
            acc[mt][ntl] = __builtin_amdgcn_mfma_f32_16x16x32_bf16(Ah, Bh[ntl],
                                                                   acc[mt][ntl], 0, 0, 0);
            acc[mt][ntl] = __builtin_amdgcn_mfma_f32_16x16x32_bf16(Ah, Bl[ntl],
                                                                   acc[mt][ntl], 0, 0, 0);
            acc[mt][ntl] = __builtin_amdgcn_mfma_f32_16x16x32_bf16(Al, Bh[ntl],
                                                                   acc[mt][ntl], 0, 0, 0);
          }
        }
      }
      __syncthreads();
    }
  }
  float a = alpha[0];
#pragma unroll
  for (int mt = 0; mt < 4; ++mt)
#pragma unroll
    for (int ntl = 0; ntl < 2; ++ntl)
#pragma unroll
      for (int r = 0; r < 4; ++r) {
        int px = pxb + mt * 16 + lg * 4 + r;    // D row = (lane>>4)*4 + reg
        int co = coh * 32 + ntl * 16 + lm;      // D col = lane&15
        float v = acc[mt][ntl][r] + bias[co];
        v = v >= 0.f ? v : a * v;
        unsigned short h = bf16_rne(v);
        unsigned short lo = bf16_rne(v - __uint_as_float((unsigned)h << 16));
        size_t idx = ((size_t)(b * 134 + y + 3) * 134 + px + 3) * 64 + co;
        outh[idx] = h;
        outl[idx] = lo;
      }
}

// ======= MFMA conv5 (64->8) + PReLU + fused GCN lin (8->10) -> xl (f32) =======
__global__ __launch_bounds__(256) void k_convm5(
    const unsigned short* __restrict__ inh, const unsigned short* __restrict__ inl,
    const unsigned short* __restrict__ wpk, const float* __restrict__ b5,
    const float* __restrict__ p5, const float* __restrict__ gw,
    float* __restrict__ xl) {
  int i0 = (int)((blockIdx.x & 7) * 64 + (blockIdx.x >> 3));
  int b = i0 >> 7, y = i0 & 127;
  int tid = threadIdx.x, l = tid & 63;
  int wv = tid >> 6;
  int pxb = wv * 32;
  int lg = l >> 4, lm = l & 15;

  __shared__ unsigned short hbuf[2][134 * 44];
  __shared__ unsigned short lbuf[2][134 * 44];
  __shared__ float feat[128][9];

  f32x4 acc[2];
  acc[0] = (f32x4){0.f, 0.f, 0.f, 0.f};
  acc[1] = (f32x4){0.f, 0.f, 0.f, 0.f};

  for (int ch = 0; ch < 64; ch += 32) {
    auto stage = [&](int ky, int s) {
      const unsigned short* gh = inh + ((size_t)(b * 134 + y + ky) * 134) * 64 + ch;
      const unsigned short* gl = inl + ((size_t)(b * 134 + y + ky) * 134) * 64 + ch;
      for (int i = tid; i < 134 * 4; i += 256) {
        int px = i >> 2, q = i & 3;
        bf16x8 vh = *(const bf16x8*)(gh + px * 64 + q * 8);
        bf16x8 vl = *(const bf16x8*)(gl + px * 64 + q * 8);
        *(bf16x8*)&hbuf[s][px * 44 + q * 8] = vh;
        *(bf16x8*)&lbuf[s][px * 44 + q * 8] = vl;
      }
    };
    stage(0, 0);
    __syncthreads();
    for (int ky = 0; ky < 7; ++ky) {
      if (ky < 6) stage(ky + 1, (ky + 1) & 1);
      int s = ky & 1;
#pragma unroll
      for (int kx = 0; kx < 7; ++kx) {
        int tap = ky * 7 + kx;
        const unsigned short* wt =
            wpk + (size_t)((tap * 2 + (ch >> 5)) * 2) * 512 + (size_t)l * 8;
        bf16x8 Bh = *(const bf16x8*)(wt);
        bf16x8 Bl = *(const bf16x8*)(wt + 512);
#pragma unroll
        for (int mt = 0; mt < 2; ++mt) {
          int px = pxb + mt * 16 + lm + kx;
          bf16x8 Ah = *(const bf16x8*)&hbuf[s][px * 44 + lg * 8];
          bf16x8 Al = *(const bf16x8*)&lbuf[s][px * 44 + lg * 8];
          acc[mt] = __builtin_amdgcn_mfma_f32_16x16x32_bf16(Ah, Bh, acc[mt], 0, 0, 0);
          acc[mt] = __builtin_amdgcn_mfma_f32_16x16x32_bf16(Ah, Bl, acc[mt], 0, 0, 0);
          acc[mt] = __builtin_amdgcn_mfma_f32_16x16x32_bf16(Al, Bh, acc[mt], 0, 0, 0);
        }
      }
      __syncthreads();
    }
  }
  float a = p5[0];
  if (lm < 8) {
#pragma unroll
    for (int mt = 0; mt < 2; ++mt)
#pragma unroll
      for (int r = 0; r < 4; ++r) {
        int px = pxb + mt * 16 + lg * 4 + r;
        float v = acc[mt][r] + b5[lm];
        feat[px][lm] = v >= 0.f ? v : a * v;
      }
  }
  __syncthreads();
  if (tid < 128) {
    int px = tid;
    float o[10];
#pragma unroll
    for (int f = 0; f < 10; ++f) o[f] = 0.f;
#pragma unroll
    for (int c = 0; c < 8; ++c) {
      float fv = feat[px][c];
#pragma unroll
      for (int f = 0; f < 10; ++f) o[f] += fv * gw[c * 10 + f];
    }
    float* op = xl + ((size_t)b * 16384 + y * 128 + px) * 10;
#pragma unroll
    for (int f = 0; f < 10; ++f) op[f] = o[f];
  }
}

// ======= MFMA sr1: 16->64, 9x9 (kx padded to 10, paired taps -> K=32) =======
__global__ __launch_bounds__(256) void k_convs(
    const float* __restrict__ imgp, const unsigned short* __restrict__ wpk,
    const float* __restrict__ bias, const float* __restrict__ alpha,
    float* __restrict__ out) {
  int i0 = (int)((blockIdx.x & 7) * 64 + (blockIdx.x >> 3));
  int b = i0 >> 7, y = i0 & 127;
  int tid = threadIdx.x, l = tid & 63;
  int wv = tid >> 6, wbase = wv * 32;
  int lg = l >> 4, lm = l & 15;

  __shared__ unsigned short hbuf[2][137 * 20];
  __shared__ unsigned short lbuf[2][137 * 20];

  f32x4 acc[2][4];
#pragma unroll
  for (int mt = 0; mt < 2; ++mt)
#pragma unroll
    for (int nt = 0; nt < 4; ++nt) acc[mt][nt] = (f32x4){0.f, 0.f, 0.f, 0.f};

  auto stage = [&](int ky, int s) {  // input row y+ky -> slot s (px 136 zeroed)
    const float* gin = imgp + ((size_t)(b * 136 + y + ky) * 136) * 16;
    for (int i = tid; i < 137 * 4; i += 256) {
      int px = i >> 2, q = i & 3;
      float4 v = (px < 136) ? *(const float4*)(gin + px * 16 + q * 4)
                            : make_float4(0.f, 0.f, 0.f, 0.f);
      unsigned short h0 = bf16_rne(v.x), h1 = bf16_rne(v.y);
      unsigned short h2 = bf16_rne(v.z), h3 = bf16_rne(v.w);
      unsigned short l0 = bf16_rne(v.x - __uint_as_float((unsigned)h0 << 16));
      unsigned short l1 = bf16_rne(v.y - __uint_as_float((unsigned)h1 << 16));
      unsigned short l2 = bf16_rne(v.z - __uint_as_float((unsigned)h2 << 16));
      unsigned short l3 = bf16_rne(v.w - __uint_as_float((unsigned)h3 << 16));
      *(ushort4*)&hbuf[s][px * 20 + q * 4] = make_ushort4(h0, h1, h2, h3);
      *(ushort4*)&lbuf[s][px * 20 + q * 4] = make_ushort4(l0, l1, l2, l3);
    }
  };
  stage(0, 0);
  __syncthreads();
  for (int ky = 0; ky < 9; ++ky) {
    if (ky < 8) stage(ky + 1, (ky + 1) & 1);
    int s = ky & 1;
#pragma unroll
    for (int p = 0; p < 5; ++p) {
      const unsigned short* wt =
          wpk + ((size_t)(ky * 5 + p) * 8) * 512 + (size_t)l * 8;
      bf16x8 Bh[4], Bl[4];
#pragma unroll
      for (int nt = 0; nt < 4; ++nt) {
        Bh[nt] = *(const bf16x8*)(wt + (nt * 2 + 0) * 512);
        Bl[nt] = *(const bf16x8*)(wt + (nt * 2 + 1) * 512);
      }
#pragma unroll
      for (int mt = 0; mt < 2; ++mt) {
        int px = wbase + mt * 16 + lm + 2 * p + (lg >> 1);
        bf16x8 Ah = *(const bf16x8*)&hbuf[s][px * 20 + (lg & 1) * 8];
        bf16x8 Al = *(const bf16x8*)&lbuf[s][px * 20 + (lg & 1) * 8];
#pragma unroll
        for (int nt = 0; nt < 4; ++nt) {
          acc[mt][nt] =
              __builtin_amdgcn_mfma_f32_16x16x32_bf16(Ah, Bh[nt], acc[mt][nt], 0, 0, 0);
          acc[mt][nt] =
              __builtin_amdgcn_mfma_f32_16x16x32_bf16(Ah, Bl[nt], acc[mt][nt], 0, 0, 0);
          acc[mt][nt] =
              __builtin_amdgcn_mfma_f32_16x16x32_bf16(Al, Bh[nt], acc[mt][nt], 0, 0, 0);
        }
      }
    }
    __syncthreads();
  }
  float a = alpha[0];
#pragma unroll
  for (int mt = 0; mt < 2; ++mt)
#pragma unroll
    for (int nt = 0; nt < 4; ++nt)
#pragma unroll
      for (int r = 0; r < 4; ++r) {
        int px = wbase + mt * 16 + lg * 4 + r;
        int co = nt * 16 + lm;
        float v = acc[mt][nt][r] + bias[co];
        out[((size_t)(b * 128 + y) * 128 + px) * 64 + co] = v >= 0.f ? v : a * v;
      }
}

// --- 2-row conv, NHWC, f32: P=4 (2 rows x 2 px per lane), SGPR weights, CH-split K ---
template <int CIN, int COUT, int KS, int IN_H, int IN_W, int OUT_H, int OUT_W,
          int OUT_OFF, int STR, int CH, int NSPLIT>
__global__ __launch_bounds__(64 * NSPLIT) void k_conv3(
    const float* __restrict__ in, const float* __restrict__ wT,
    const float* __restrict__ bias, const float* __restrict__ alpha,
    float* __restrict__ out) {
  constexpr int C = COUT / NSPLIT;
  int b = blockIdx.x >> 6, y0 = (blockIdx.x & 63) * 2;
  int l = threadIdx.x & 63;
  int cob = __builtin_amdgcn_readfirstlane((int)(threadIdx.x >> 6) * C);
  __shared__ float sbuf[2][IN_W * STR];
  float acc[4][C];
#pragma unroll
  for (int r = 0; r < 4; ++r)
#pragma unroll
    for (int i = 0; i < C; ++i) acc[r][i] = 0.f;

  for (int ch = 0; ch < CIN; ch += CH) {
    auto stage = [&](int k) {
      const float* gin = in + ((size_t)(b * IN_H + y0 + k) * IN_W) * CIN + ch;
      float* dst = sbuf[k & 1];
      constexpr int N4 = IN_W * CH / 4;
      for (int i = threadIdx.x; i < N4; i += 64 * NSPLIT) {
        int xx = i / (CH / 4), c4 = (i - xx * (CH / 4)) * 4;
        float4 v = *(const float4*)(gin + (size_t)xx * CIN + c4);
        *(float4*)(dst + xx * STR + c4) = v;
      }
    };
    stage(0);
    stage(1);
    __syncthreads();
    for (int ky = 0; ky < KS; ++ky) {
      const float* sA = sbuf[ky & 1];
      const float* sB = sbuf[(ky + 1) & 1];
      for (int kx = 0; kx < KS; ++kx) {
        const float* wt = wT + ((size_t)(ky * KS + kx) * CIN + ch) * COUT + cob;
        const float* a0p = sA + (l + kx) * STR;
        const float* a1p = sA + (l + 64 + kx) * STR;
        const float* b0p = sB + (l + kx) * STR;
        const float* b1p = sB + (l + 64 + kx) * STR;
#pragma unroll
        for (int ci = 0; ci < CH; ci += 4) {
          float4 a0 = *(const float4*)(a0p + ci);
          float4 a1 = *(const float4*)(a1p + ci);
          float4 b0 = *(const float4*)(b0p + ci);
          float4 b1 = *(const float4*)(b1p + ci);
#pragma unroll
          for (int c = 0; c < 4; ++c) {
            const float* wr = wt + (size_t)(ci + c) * COUT;
            float va0 = ((const float*)&a0)[c], va1 = ((const float*)&a1)[c];
            float vb0 = ((const float*)&b0)[c], vb1 = ((const float*)&b1)[c];
#pragma unroll
            for (int co = 0; co < C; ++co) {
              float w = wr[co];
              acc[0][co] += va0 * w;
              acc[1][co] += va1 * w;
              acc[2][co] += vb0 * w;
              acc[3][co] += vb1 * w;
            }
          }
        }
      }
      __syncthreads();
      if (ky < KS - 1) {
        stage(ky + 2);
        __syncthreads();
      }
    }
  }
  float a = alpha[0];
#pragma unroll
  for (int r = 0; r < 2; ++r) {
    float* rowp =
        out + (((size_t)(b * OUT_H + y0 + r + OUT_OFF)) * OUT_W + OUT_OFF) * COUT + cob;
#pragma unroll
    for (int p = 0; p < 2; ++p) {
      float* op = rowp + (size_t)(l + p * 64) * COUT;
#pragma unroll
      for (int co = 0; co < C; ++co) {
        float v = acc[r * 2 + p][co] + bias[cob + co];
        op[co] = v >= 0.f ? v : a * v;
      }
    }
  }
}

// ------- single-row conv (kept for sr3: COUT=1), pixel-pair, SGPR weights ----------
template <int CIN, int COUT, int KS, int IN_H, int IN_W, int OUT_H, int OUT_W,
          int OUT_OFF, int STR, int NSPLIT>
__global__ __launch_bounds__(64 * NSPLIT) void k_conv2(
    const float* __restrict__ in, const float* __restrict__ wT,
    const float* __restrict__ bias, const float* __restrict__ alpha,
    float* __restrict__ out) {
  constexpr int C = COUT / NSPLIT;
  int b = blockIdx.x >> 7, y = blockIdx.x & 127;
  int l = threadIdx.x & 63;
  int cob = __builtin_amdgcn_readfirstlane((int)(threadIdx.x >> 6) * C);
  __shared__ float srow[IN_W * STR];
  float acc0[C], acc1[C];
#pragma unroll
  for (int i = 0; i < C; ++i) acc0[i] = acc1[i] = 0.f;

  for (int ky = 0; ky < KS; ++ky) {
    __syncthreads();
    const float* gin = in + (size_t)(b * IN_H + y + ky) * IN_W * CIN;
    constexpr int N4 = IN_W * CIN / 4;
    for (int i = threadIdx.x; i < N4; i += 64 * NSPLIT) {
      float4 v = *(const float4*)(gin + (size_t)i * 4);
      int xx = (i * 4) / CIN, cc = (i * 4) % CIN;
      *(float4*)(srow + xx * STR + cc) = v;
    }
    __syncthreads();
    for (int kx = 0; kx < KS; ++kx) {
      const float* wt = wT + ((size_t)(ky * KS + kx) * CIN) * COUT + cob;
      const float* s0 = srow + (l + kx) * STR;
      const float* s1 = srow + (l + 64 + kx) * STR;
      for (int ci = 0; ci < CIN; ci += 4) {
        float4 a0 = *(const float4*)(s0 + ci);
        float4 a1 = *(const float4*)(s1 + ci);
#pragma unroll
        for (int c = 0; c < 4; ++c) {
          float v0 = ((const float*)&a0)[c];
          float v1 = ((const float*)&a1)[c];
          const float* wr = wt + (size_t)(ci + c) * COUT;
#pragma unroll
          for (int co = 0; co < C; ++co) {
            float w = wr[co];
            acc0[co] += v0 * w;
            acc1[co] += v1 * w;
          }
        }
      }
    }
  }
  float a = alpha[0];
  float* rowp = out + ((size_t)(b * OUT_H + y + OUT_OFF) * OUT_W + OUT_OFF) * COUT + cob;
  float* op0 = rowp + (size_t)l * COUT;
  float* op1 = rowp + (size_t)(l + 64) * COUT;
#pragma unroll
  for (int co = 0; co < C; ++co) {
    float bi = bias[cob + co];
    float v0 = acc0[co] + bi;
    float v1 = acc1[co] + bi;
    op0[co] = v0 >= 0.f ? v0 : a * v0;
    op1[co] = v1 >= 0.f ? v1 : a * v1;
  }
}

// ====== GCN edge pipeline, LDS-privatized ======
template <int HALF>
__global__ __launch_bounds__(1024) void k_degp(
    const int* __restrict__ ei, const float* __restrict__ ew,
    float* __restrict__ pdeg, int* __restrict__ cnt, int* __restrict__ rank, int E) {
  __shared__ float degl[16384];
  for (int i = threadIdx.x; i < 16384; i += 1024) degl[i] = 0.f;
  __syncthreads();
  int chunk = (E + gridDim.x - 1) / gridDim.x;
  int base = blockIdx.x * chunk;
  int end = min(E, base + chunk);
  for (int e = base + (int)threadIdx.x; e < end; e += 1024) {
    int col = ei[E + e];
    float w = ew[e];
    if ((col >> 14) == HALF) atomicAdd(&degl[col & 16383], w);
    if (HALF == 1) {
      int row = ei[e];
      if (row < NS && col >= NS) rank[e] = atomicAdd(&cnt[col - NS], 1);
    }
  }
  __syncthreads();
  float* pd = pdeg + (size_t)blockIdx.x * 16384;
  for (int i = threadIdx.x; i < 16384; i += 1024) pd[i] = degl[i];
}

__global__ void k_dis2(const float* __restrict__ pdegA, const float* __restrict__ pdegB,
                       float* __restrict__ dis, int nb) {
  int n = blockIdx.x * 256 + threadIdx.x;
  if (n >= 2 * NS) return;
  const float* p = (n < NS ? pdegA : pdegB) + (n & 16383);
  float s = 1.0f;
  for (int b = 0; b < nb; ++b) s += p[(size_t)b * 16384];
  dis[n] = rsqrtf(s);
}

__global__ __launch_bounds__(1024) void k_scan(const int* __restrict__ cnt,
                                               int* __restrict__ ptr) {
  __shared__ int ps[1024];
  int tid = threadIdx.x;
  int base = tid * 16;
  int v[16];
  int s = 0;
#pragma unroll
  for (int k = 0; k < 16; ++k) {
    v[k] = s;
    s += cnt[base + k];
  }
  ps[tid] = s;
  __syncthreads();
  for (int off = 1; off < 1024; off <<= 1) {
    int t = (tid >= off) ? ps[tid - off] : 0;
    __syncthreads();
    ps[tid] += t;
    __syncthreads();
  }
  int chunkoff = (tid == 0) ? 0 : ps[tid - 1];
#pragma unroll
  for (int k = 0; k < 16; ++k) ptr[base + k] = chunkoff + v[k];
  if (tid == 1023) ptr[16384] = ps[1023];
}

__global__ void k_bucket2(const int* __restrict__ ei, const float* __restrict__ ew,
                          const float* __restrict__ dis, const int* __restrict__ ptr,
                          const int* __restrict__ rank, int* __restrict__ erow,
                          float* __restrict__ enrm, int E) {
  int e = blockIdx.x * 256 + threadIdx.x;
  if (e >= E) return;
  int row = ei[e], col = ei[E + e];
  if (row >= NS || col < NS) return;
  int cp = col - NS;
  int pos = ptr[cp] + rank[e];
  erow[pos] = row;
  enrm[pos] = dis[row] * ew[e] * dis[col];
}

__global__ __launch_bounds__(256) void k_gather(
    const int* __restrict__ ptr, const int* __restrict__ erow,
    const float* __restrict__ enrm, const float* __restrict__ xl,
    const float* __restrict__ gb, float* __restrict__ imgp) {
  int cp = blockIdx.x * 4 + (threadIdx.x >> 6);
  int l = threadIdx.x & 63;
  int b = l >> 4, f = l & 15;
  bool act = f < 10;
  float acc = 0.f;
  int s = ptr[cp], e1 = ptr[cp + 1];
  for (int e = s; e < e1; ++e) {
    int row = erow[e];
    float nrm = enrm[e];
    if (act) acc += xl[((size_t)b * 16384 + row) * 10 + f] * nrm;
  }
  if (act) {
    int y = cp >> 7, x = cp & 127;
    imgp[((size_t)(b * 136 + y + 4) * 136 + x + 4) * 16 + f] = acc + gb[f];
  }
}

// ---------------- launcher ----------------
extern "C" void kernel_launch(void* const* d_in, const int* in_sizes, int n_in,
                              void* d_out, int out_size, void* d_ws, size_t ws_size,
                              hipStream_t stream) {
  const float* sino = (const float*)d_in[0];
  const int* ei = (const int*)d_in[1];
  const float* ew = (const float*)d_in[2];
  const float* w1 = (const float*)d_in[3];
  const float* w2 = (const float*)d_in[4];
  const float* w3 = (const float*)d_in[5];
  const float* w4 = (const float*)d_in[6];
  const float* w5 = (const float*)d_in[7];
  const float* gw = (const float*)d_in[8];
  const float* sw1 = (const float*)d_in[9];
  const float* sw2 = (const float*)d_in[10];
  const float* sw3 = (const float*)d_in[11];
  const float* b1 = (const float*)d_in[12];
  const float* b2 = (const float*)d_in[13];
  const float* b3 = (const float*)d_in[14];
  const float* b4 = (const float*)d_in[15];
  const float* b5 = (const float*)d_in[16];
  const float* sb1 = (const float*)d_in[17];
  const float* sb2 = (const float*)d_in[18];
  const float* sb3 = (const float*)d_in[19];
  const float* gb = (const float*)d_in[20];
  const float* bng = (const float*)d_in[21];
  const float* bnb = (const float*)d_in[22];
  const float* p1 = (const float*)d_in[23];
  const float* p2 = (const float*)d_in[24];
  const float* p3 = (const float*)d_in[25];
  const float* p4 = (const float*)d_in[26];
  const float* p5 = (const float*)d_in[27];
  const float* sp1 = (const float*)d_in[28];
  const float* sp2 = (const float*)d_in[29];
  const float* sp3 = (const float*)d_in[30];
  const int E = in_sizes[2];

  char* ws = (char*)d_ws;
  size_t off = 0;
  auto alloc = [&](size_t bytes) {
    char* p = ws + off;
    off += (bytes + 255) & ~(size_t)255;
    return p;
  };
  const size_t PL = (size_t)4 * 134 * 134 * 64;  // plane elements
  float* x1p = (float*)alloc(PL * 4);
  unsigned short* xh1 = (unsigned short*)alloc(PL * 2);
  unsigned short* xl1 = (unsigned short*)alloc(PL * 2);
  unsigned short* xh2 = (unsigned short*)alloc(PL * 2);
  unsigned short* xl2 = (unsigned short*)alloc(PL * 2);
  unsigned short* wpk2 = (unsigned short*)alloc(401408 * 2);
  unsigned short* wpk3 = (unsigned short*)alloc(401408 * 2);
  unsigned short* wpk4 = (unsigned short*)alloc(401408 * 2);
  unsigned short* wpk5 = (unsigned short*)alloc(100352 * 2);
  unsigned short* wpks1 = (unsigned short*)alloc(184320 * 2);
  float* wt1 = (float*)alloc(3136 * 4);
  float* wts2 = (float*)alloc(2048 * 4);
  float* wts3 = (float*)alloc(800 * 4);
  double* bnsum = (double*)alloc(128 * 8);
  float* bnsc = (float*)alloc(128 * 4);
  float* xl = (float*)alloc((size_t)4 * 16384 * 10 * 4);
  float* pdegA = (float*)alloc((size_t)64 * 16384 * 4);
  float* pdegB = (float*)alloc((size_t)64 * 16384 * 4);
  float* dis = (float*)alloc(32768 * 4);
  int* cnt = (int*)alloc(16384 * 4);
  int* ptr = (int*)alloc(16385 * 4);
  int* rank = (int*)alloc((size_t)E * 4);
  int* erow = (int*)alloc((size_t)E * 4);
  float* enrm = (float*)alloc((size_t)E * 4);
  float* imgp = (float*)alloc((size_t)4 * 136 * 136 * 16 * 4);
  float* s1 = (float*)alloc((size_t)4 * 128 * 128 * 64 * 4);
  float* s2p = (float*)alloc((size_t)4 * 132 * 132 * 32 * 4);

  // zero plane halos / accumulators (bf16 zero == 0x0000)
  hipMemsetAsync(xh1, 0, PL * 2, stream);
  hipMemsetAsync(xl1, 0, PL * 2, stream);
  hipMemsetAsync(xh2, 0, PL * 2, stream);
  hipMemsetAsync(xl2, 0, PL * 2, stream);
  hipMemsetAsync(bnsum, 0, 128 * 8, stream);
  hipMemsetAsync(cnt, 0, 16384 * 4, stream);
  hipMemsetAsync(imgp, 0, (size_t)4 * 136 * 136 * 16 * 4, stream);
  hipMemsetAsync(s2p, 0, (size_t)4 * 132 * 132 * 32 * 4, stream);

  // weight prep
  k_wpack<<<784, 256, 0, stream>>>(w2, wpk2);
  k_wpack<<<784, 256, 0, stream>>>(w3, wpk3);
  k_wpack<<<784, 256, 0, stream>>>(w4, wpk4);
  k_wpack5<<<392, 256, 0, stream>>>(w5, wpk5);
  k_wpacks<<<720, 256, 0, stream>>>(sw1, wpks1);
  k_wtrans<<<13, 256, 0, stream>>>(w1, wt1, 64, 1, 1, 7);
  k_wtrans<<<8, 256, 0, stream>>>(sw2, wts2, 32, 64, 64, 1);
  k_wtrans<<<4, 256, 0, stream>>>(sw3, wts3, 1, 32, 32, 5);

  k_conv1<<<512, 128, 0, stream>>>(sino, wt1, b1, p1, x1p);
  k_bnstats<<<128, 256, 0, stream>>>(x1p, bnsum);
  k_bnfinal<<<1, 64, 0, stream>>>(bnsum, bnsc, bng, bnb);
  // BN on interior -> hi/lo planes (halo stays zero; ref zero-pads AFTER BN).
  k_bnapply<<<4096, 256, 0, stream>>>(x1p, bnsc, xh1, xl1);

  // MFMA split-bf16 convs on bf16-plane IO, XCD-swizzled, co-split waves (R17)
  k_convm<<<512, 256, 0, stream>>>(xh1, xl1, wpk2, b2, p2, xh2, xl2);
  k_convm<<<512, 256, 0, stream>>>(xh2, xl2, wpk3, b3, p3, xh1, xl1);
  k_convm<<<512, 256, 0, stream>>>(xh1, xl1, wpk4, b4, p4, xh2, xl2);
  // conv5 + GCN lin via MFMA
  k_convm5<<<512, 256, 0, stream>>>(xh2, xl2, wpk5, b5, p5, gw, xl);

  // edge pipeline: LDS-privatized deg partials + fused CSR rank (64 partials)
  k_degp<0><<<64, 1024, 0, stream>>>(ei, ew, pdegA, cnt, rank, E);
  k_degp<1><<<64, 1024, 0, stream>>>(ei, ew, pdegB, cnt, rank, E);
  k_dis2<<<128, 256, 0, stream>>>(pdegA, pdegB, dis, 64);
  k_scan<<<1, 1024, 0, stream>>>(cnt, ptr);
  k_bucket2<<<(E + 255) / 256, 256, 0, stream>>>(ei, ew, dis, ptr, rank, erow, enrm, E);
  k_gather<<<4096, 256, 0, stream>>>(ptr, erow, enrm, xl, gb, imgp);

  // sr1 via MFMA paired-tap kernel
  k_convs<<<512, 256, 0, stream>>>(imgp, wpks1, sb1, sp1, s1);
  k_conv3<64, 32, 1, 128, 128, 132, 132, 2, 36, 32, 8>
      <<<256, 512, 0, stream>>>(s1, wts2, sb2, sp2, s2p);
  k_conv2<32, 1, 5, 132, 132, 128, 128, 0, 36, 1>
      <<<512, 64, 0, stream>>>(s2p, wts3, sb3, sp3, (float*)d_out);
}

// Round 20
// 619.045 us; speedup vs baseline: 1.7037x; 1.0221x over previous
//
#include <hip/hip_runtime.h>

static constexpr int NS = 16384;

typedef __attribute__((ext_vector_type(8))) short bf16x8;   // 8 bf16 / 16B copy unit
typedef __attribute__((ext_vector_type(4))) float f32x4;    // 4 f32 acc

__device__ inline unsigned short bf16_rne(float x) {
  unsigned u = __float_as_uint(x);
  unsigned r = u + 0x7FFF + ((u >> 16) & 1);
  return (unsigned short)(r >> 16);
}

// ------------- weight transpose: w[co][ci][ky][kx] (f32) -> wT[t][ci][co] (f32)
__global__ void k_wtrans(const float* __restrict__ w, float* __restrict__ wT,
                         int CO, int CI_IN, int CI_OUT, int KS) {
  int i = blockIdx.x * 256 + threadIdx.x;
  int tot = KS * KS * CI_OUT * CO;
  if (i >= tot) return;
  int co = i % CO;
  int r = i / CO;
  int ci = r % CI_OUT;
  int t = r / CI_OUT;
  int ky = t / KS, kx = t % KS;
  float v = 0.f;
  if (ci < CI_IN) v = w[((co * CI_IN + ci) * KS + ky) * KS + kx];
  wT[i] = v;
}

// ---- pack 64x64 7x7 weights into MFMA B-frag order, split hi/lo bf16 ----
__global__ void k_wpack(const float* __restrict__ w, unsigned short* __restrict__ wpk) {
  int i = blockIdx.x * 256 + threadIdx.x;
  if (i >= 49 * 64 * 64) return;
  int co = i & 63, r = i >> 6;
  int ci = r & 63, tap = r >> 6;
  float v = w[(co * 64 + ci) * 49 + tap];
  unsigned short hi = bf16_rne(v);
  float hif = __uint_as_float((unsigned)hi << 16);
  unsigned short lo = bf16_rne(v - hif);
  int ks = ci >> 5, k32 = ci & 31;
  int lane = ((k32 >> 3) << 4) | (co & 15);
  int j = ci & 7, nt = co >> 4;
  size_t base = ((size_t)(((tap * 2 + ks) * 4 + nt) * 2) * 64 + lane) * 8 + j;
  wpk[base] = hi;
  wpk[base + 512] = lo;
}

// ---- pack conv5 weights (8,64,7,7) into B-frags: f = (tap*2+ks)*2+sp ----
__global__ void k_wpack5(const float* __restrict__ w5,
                         unsigned short* __restrict__ wpk) {
  int i = blockIdx.x * 256 + threadIdx.x;
  if (i >= 196 * 512) return;
  int j = i & 7, l = (i >> 3) & 63, f = i >> 9;
  int sp = f & 1, r = f >> 1;
  int ks = r & 1, tap = r >> 1;
  int co = l & 15;
  int k32 = ((l >> 4) << 3) + j;
  int ci = ks * 32 + k32;
  float v = (co < 8) ? w5[(co * 64 + ci) * 49 + tap] : 0.f;
  unsigned short hi = bf16_rne(v);
  unsigned short outv;
  if (sp == 0) {
    outv = hi;
  } else {
    float hif = __uint_as_float((unsigned)hi << 16);
    outv = bf16_rne(v - hif);
  }
  wpk[i] = outv;
}

// ---- pack sr1 weights (64,10,9,9) into paired-tap MFMA B-frags, split hi/lo ----
__global__ void k_wpacks(const float* __restrict__ sw1,
                         unsigned short* __restrict__ wpk) {
  int i = blockIdx.x * 256 + threadIdx.x;
  if (i >= 360 * 512) return;
  int j = i & 7, l = (i >> 3) & 63, f = i >> 9;
  int sp = f & 1, nt = (f >> 1) & 3;
  int r3 = f >> 3, p = r3 % 5, ky = r3 / 5;
  int co = nt * 16 + (l & 15);
  int k = ((l >> 4) << 3) + j;
  int kx = 2 * p + (k >> 4);
  int ci = k & 15;
  float v = (ci < 10 && kx < 9) ? sw1[((co * 10 + ci) * 9 + ky) * 9 + kx] : 0.f;
  unsigned short hi = bf16_rne(v);
  unsigned short outv;
  if (sp == 0) {
    outv = hi;
  } else {
    float hif = __uint_as_float((unsigned)hi << 16);
    outv = bf16_rne(v - hif);
  }
  wpk[i] = outv;
}

// ---------------- conv1: 1->64, 7x7, pad3, +bias +PReLU -> f32 NHWC (interior) ------
__global__ __launch_bounds__(128) void k_conv1(
    const float* __restrict__ sino, const float* __restrict__ wT1,
    const float* __restrict__ b1, const float* __restrict__ p1,
    float* __restrict__ out) {
  int b = blockIdx.x >> 7, y = blockIdx.x & 127, x = threadIdx.x;
  float acc[64];
#pragma unroll
  for (int i = 0; i < 64; ++i) acc[i] = 0.f;
#pragma unroll
  for (int ky = 0; ky < 7; ++ky) {
    int yy = y + ky - 3;
#pragma unroll
    for (int kx = 0; kx < 7; ++kx) {
      int xx = x + kx - 3;
      float v = (yy >= 0 && yy < 128 && xx >= 0 && xx < 128)
                    ? sino[(b * 128 + yy) * 128 + xx]
                    : 0.f;
      const float* wr = wT1 + (ky * 7 + kx) * 64;
#pragma unroll
      for (int co = 0; co < 64; ++co) acc[co] += v * wr[co];
    }
  }
  float a = p1[0];
  float* op = out + ((size_t)(b * 134 + y + 3) * 134 + x + 3) * 64;
#pragma unroll
  for (int co = 0; co < 64; ++co) {
    float v = acc[co] + b1[co];
    op[co] = v >= 0.f ? v : a * v;
  }
}

// ---------------- BN stats in f64 (sum, sumsq per channel) ----------------
__global__ __launch_bounds__(256) void k_bnstats(const float* __restrict__ x1p,
                                                 double* __restrict__ bnsum) {
  int c = threadIdx.x & 63, sl = threadIdx.x >> 6;
  double s = 0.0, q = 0.0;
  int base = blockIdx.x * 512 + sl * 128;
  for (int i = 0; i < 128; ++i) {
    int p = base + i;
    int b = p >> 14, y = (p >> 7) & 127, x = p & 127;
    double v = (double)x1p[((size_t)(b * 134 + y + 3) * 134 + x + 3) * 64 + c];
    s += v;
    q += v * v;
  }
  __shared__ double red[2][4][64];
  red[0][sl][c] = s;
  red[1][sl][c] = q;
  __syncthreads();
  if (sl == 0) {
    s = red[0][0][c] + red[0][1][c] + red[0][2][c] + red[0][3][c];
    q = red[1][0][c] + red[1][1][c] + red[1][2][c] + red[1][3][c];
    atomicAdd(&bnsum[c], s);
    atomicAdd(&bnsum[64 + c], q);
  }
}

__global__ void k_bnfinal(const double* __restrict__ bnsum, float* __restrict__ bnsc,
                          const float* __restrict__ g, const float* __restrict__ bb) {
  int c = threadIdx.x;
  if (c >= 64) return;
  double m = bnsum[c] * (1.0 / 65536.0);
  double v = bnsum[64 + c] * (1.0 / 65536.0) - m * m;
  double sc = (double)g[c] * rsqrt(v + 1e-5);
  bnsc[c] = (float)sc;
  bnsc[64 + c] = (float)((double)bb[c] - m * sc);
}

// ---- BN applied to INTERIOR of x1p, emitting hi/lo bf16 planes (halo pre-zeroed) ----
__global__ __launch_bounds__(256) void k_bnapply(
    const float* __restrict__ x1p, const float* __restrict__ bnsc,
    unsigned short* __restrict__ oh, unsigned short* __restrict__ ol) {
  int i = blockIdx.x * 256 + threadIdx.x;  // over 4*128*128*16 float4 groups
  if (i >= 4 * 128 * 128 * 16) return;
  int g = i & 15, p = i >> 4;
  int b = p >> 14, y = (p >> 7) & 127, x = p & 127;
  size_t base = ((size_t)(b * 134 + y + 3) * 134 + x + 3) * 64 + g * 4;
  float4 v = *(const float4*)(x1p + base);
  int c = g * 4;
  v.x = v.x * bnsc[c + 0] + bnsc[64 + c + 0];
  v.y = v.y * bnsc[c + 1] + bnsc[64 + c + 1];
  v.z = v.z * bnsc[c + 2] + bnsc[64 + c + 2];
  v.w = v.w * bnsc[c + 3] + bnsc[64 + c + 3];
  unsigned short h0 = bf16_rne(v.x), h1 = bf16_rne(v.y);
  unsigned short h2 = bf16_rne(v.z), h3 = bf16_rne(v.w);
  unsigned short l0 = bf16_rne(v.x - __uint_as_float((unsigned)h0 << 16));
  unsigned short l1 = bf16_rne(v.y - __uint_as_float((unsigned)h1 << 16));
  unsigned short l2 = bf16_rne(v.z - __uint_as_float((unsigned)h2 << 16));
  unsigned short l3 = bf16_rne(v.w - __uint_as_float((unsigned)h3 << 16));
  *(ushort4*)(oh + base) = make_ushort4(h0, h1, h2, h3);
  *(ushort4*)(ol + base) = make_ushort4(l0, l1, l2, l3);
}

// ======= MFMA conv 64->64 7x7, split-bf16 plane IO, co-split waves (R17 proven) =====
__global__ __launch_bounds__(256) void k_convm(
    const unsigned short* __restrict__ inh, const unsigned short* __restrict__ inl,
    const unsigned short* __restrict__ wpk, const float* __restrict__ bias,
    const float* __restrict__ alpha, unsigned short* __restrict__ outh,
    unsigned short* __restrict__ outl) {
  int i0 = (int)((blockIdx.x & 7) * 64 + (blockIdx.x >> 3));
  int b = i0 >> 7, y = i0 & 127;
  int tid = threadIdx.x, l = tid & 63;
  int wv = tid >> 6;
  int pxb = (wv & 1) * 64;
  int coh = wv >> 1;  // co base = coh*32
  int lg = l >> 4, lm = l & 15;

  __shared__ unsigned short hbuf[2][134 * 44];
  __shared__ unsigned short lbuf[2][134 * 44];

  f32x4 acc[4][2];
#pragma unroll
  for (int mt = 0; mt < 4; ++mt)
#pragma unroll
    for (int ntl = 0; ntl < 2; ++ntl) acc[mt][ntl] = (f32x4){0.f, 0.f, 0.f, 0.f};

  for (int ch = 0; ch < 64; ch += 32) {
    auto stage = [&](int ky, int s) {  // pure copy: 2x ushort8 per iter
      const unsigned short* gh = inh + ((size_t)(b * 134 + y + ky) * 134) * 64 + ch;
      const unsigned short* gl = inl + ((size_t)(b * 134 + y + ky) * 134) * 64 + ch;
      for (int i = tid; i < 134 * 4; i += 256) {
        int px = i >> 2, q = i & 3;
        bf16x8 vh = *(const bf16x8*)(gh + px * 64 + q * 8);
        bf16x8 vl = *(const bf16x8*)(gl + px * 64 + q * 8);
        *(bf16x8*)&hbuf[s][px * 44 + q * 8] = vh;
        *(bf16x8*)&lbuf[s][px * 44 + q * 8] = vl;
      }
    };
    stage(0, 0);
    __syncthreads();
    for (int ky = 0; ky < 7; ++ky) {
      if (ky < 6) stage(ky + 1, (ky + 1) & 1);  // overlaps with compute below
      int s = ky & 1;
#pragma unroll
      for (int kx = 0; kx < 7; ++kx) {
        int tap = ky * 7 + kx;
        const unsigned short* wt =
            wpk + (size_t)(tap * 2 + (ch >> 5)) * 8 * 512 + (size_t)l * 8;
        bf16x8 Bh[2], Bl[2];
#pragma unroll
        for (int ntl = 0; ntl < 2; ++ntl) {
          int nt = coh * 2 + ntl;
          Bh[ntl] = *(const bf16x8*)(wt + (nt * 2 + 0) * 512);
          Bl[ntl] = *(const bf16x8*)(wt + (nt * 2 + 1) * 512);
        }
#pragma unroll
        for (int mt = 0; mt < 4; ++mt) {
          int px = pxb + mt * 16 + lm + kx;
          bf16x8 Ah = *(const bf16x8*)&hbuf[s][px * 44 + lg * 8];
          bf16x8 Al = *(const bf16x8*)&lbuf[s][px * 44 + lg * 8];
#pragma unroll
          for (int ntl = 0; ntl < 2; ++ntl) {
            acc[mt][ntl] = __builtin_amdgcn_mfma_f32_16x16x32_bf16(Ah, Bh[ntl],
                                                                   acc[mt][ntl], 0, 0, 0);
            acc[mt][ntl] = __builtin_amdgcn_mfma_f32_16x16x32_bf16(Ah, Bl[ntl],
                                                                   acc[mt][ntl], 0, 0, 0);
            acc[mt][ntl] = __builtin_amdgcn_mfma_f32_16x16x32_bf16(Al, Bh[ntl],
                                                                   acc[mt][ntl], 0, 0, 0);
          }
        }
      }
      __syncthreads();
    }
  }
  float a = alpha[0];
#pragma unroll
  for (int mt = 0; mt < 4; ++mt)
#pragma unroll
    for (int ntl = 0; ntl < 2; ++ntl)
#pragma unroll
      for (int r = 0; r < 4; ++r) {
        int px = pxb + mt * 16 + lg * 4 + r;    // D row = (lane>>4)*4 + reg
        int co = coh * 32 + ntl * 16 + lm;      // D col = lane&15
        float v = acc[mt][ntl][r] + bias[co];
        v = v >= 0.f ? v : a * v;
        unsigned short h = bf16_rne(v);
        unsigned short lo = bf16_rne(v - __uint_as_float((unsigned)h << 16));
        size_t idx = ((size_t)(b * 134 + y + 3) * 134 + px + 3) * 64 + co;
        outh[idx] = h;
        outl[idx] = lo;
      }
}

// ======= MFMA conv5 (64->8) + PReLU + fused GCN lin (8->10) -> xl (f32) =======
__global__ __launch_bounds__(256) void k_convm5(
    const unsigned short* __restrict__ inh, const unsigned short* __restrict__ inl,
    const unsigned short* __restrict__ wpk, const float* __restrict__ b5,
    const float* __restrict__ p5, const float* __restrict__ gw,
    float* __restrict__ xl) {
  int i0 = (int)((blockIdx.x & 7) * 64 + (blockIdx.x >> 3));
  int b = i0 >> 7, y = i0 & 127;
  int tid = threadIdx.x, l = tid & 63;
  int wv = tid >> 6;
  int pxb = wv * 32;
  int lg = l >> 4, lm = l & 15;

  __shared__ unsigned short hbuf[2][134 * 44];
  __shared__ unsigned short lbuf[2][134 * 44];
  __shared__ float feat[128][9];

  f32x4 acc[2];
  acc[0] = (f32x4){0.f, 0.f, 0.f, 0.f};
  acc[1] = (f32x4){0.f, 0.f, 0.f, 0.f};

  for (int ch = 0; ch < 64; ch += 32) {
    auto stage = [&](int ky, int s) {
      const unsigned short* gh = inh + ((size_t)(b * 134 + y + ky) * 134) * 64 + ch;
      const unsigned short* gl = inl + ((size_t)(b * 134 + y + ky) * 134) * 64 + ch;
      for (int i = tid; i < 134 * 4; i += 256) {
        int px = i >> 2, q = i & 3;
        bf16x8 vh = *(const bf16x8*)(gh + px * 64 + q * 8);
        bf16x8 vl = *(const bf16x8*)(gl + px * 64 + q * 8);
        *(bf16x8*)&hbuf[s][px * 44 + q * 8] = vh;
        *(bf16x8*)&lbuf[s][px * 44 + q * 8] = vl;
      }
    };
    stage(0, 0);
    __syncthreads();
    for (int ky = 0; ky < 7; ++ky) {
      if (ky < 6) stage(ky + 1, (ky + 1) & 1);
      int s = ky & 1;
#pragma unroll
      for (int kx = 0; kx < 7; ++kx) {
        int tap = ky * 7 + kx;
        const unsigned short* wt =
            wpk + (size_t)((tap * 2 + (ch >> 5)) * 2) * 512 + (size_t)l * 8;
        bf16x8 Bh = *(const bf16x8*)(wt);
        bf16x8 Bl = *(const bf16x8*)(wt + 512);
#pragma unroll
        for (int mt = 0; mt < 2; ++mt) {
          int px = pxb + mt * 16 + lm + kx;
          bf16x8 Ah = *(const bf16x8*)&hbuf[s][px * 44 + lg * 8];
          bf16x8 Al = *(const bf16x8*)&lbuf[s][px * 44 + lg * 8];
          acc[mt] = __builtin_amdgcn_mfma_f32_16x16x32_bf16(Ah, Bh, acc[mt], 0, 0, 0);
          acc[mt] = __builtin_amdgcn_mfma_f32_16x16x32_bf16(Ah, Bl, acc[mt], 0, 0, 0);
          acc[mt] = __builtin_amdgcn_mfma_f32_16x16x32_bf16(Al, Bh, acc[mt], 0, 0, 0);
        }
      }
      __syncthreads();
    }
  }
  float a = p5[0];
  if (lm < 8) {
#pragma unroll
    for (int mt = 0; mt < 2; ++mt)
#pragma unroll
      for (int r = 0; r < 4; ++r) {
        int px = pxb + mt * 16 + lg * 4 + r;
        float v = acc[mt][r] + b5[lm];
        feat[px][lm] = v >= 0.f ? v : a * v;
      }
  }
  __syncthreads();
  if (tid < 128) {
    int px = tid;
    float o[10];
#pragma unroll
    for (int f = 0; f < 10; ++f) o[f] = 0.f;
#pragma unroll
    for (int c = 0; c < 8; ++c) {
      float fv = feat[px][c];
#pragma unroll
      for (int f = 0; f < 10; ++f) o[f] += fv * gw[c * 10 + f];
    }
    float* op = xl + ((size_t)b * 16384 + y * 128 + px) * 10;
#pragma unroll
    for (int f = 0; f < 10; ++f) op[f] = o[f];
  }
}

// ======= MFMA sr1: 16->64, 9x9, paired taps, bf16-plane input (pure-copy stage) =====
__global__ __launch_bounds__(256) void k_convs(
    const unsigned short* __restrict__ imgph, const unsigned short* __restrict__ imgpl,
    const unsigned short* __restrict__ wpk, const float* __restrict__ bias,
    const float* __restrict__ alpha, float* __restrict__ out) {
  int i0 = (int)((blockIdx.x & 7) * 64 + (blockIdx.x >> 3));
  int b = i0 >> 7, y = i0 & 127;
  int tid = threadIdx.x, l = tid & 63;
  int wv = tid >> 6, wbase = wv * 32;
  int lg = l >> 4, lm = l & 15;

  __shared__ unsigned short hbuf[2][137 * 20];
  __shared__ unsigned short lbuf[2][137 * 20];

  f32x4 acc[2][4];
#pragma unroll
  for (int mt = 0; mt < 2; ++mt)
#pragma unroll
    for (int nt = 0; nt < 4; ++nt) acc[mt][nt] = (f32x4){0.f, 0.f, 0.f, 0.f};

  bf16x8 zz = (bf16x8){0, 0, 0, 0, 0, 0, 0, 0};
  auto stage = [&](int ky, int s) {  // input row y+ky -> slot s (px 136 zeroed)
    const unsigned short* gh = imgph + ((size_t)(b * 136 + y + ky) * 136) * 16;
    const unsigned short* gl = imgpl + ((size_t)(b * 136 + y + ky) * 136) * 16;
    for (int i = tid; i < 137 * 2; i += 256) {
      int px = i >> 1, q = i & 1;
      bf16x8 vh = (px < 136) ? *(const bf16x8*)(gh + px * 16 + q * 8) : zz;
      bf16x8 vl = (px < 136) ? *(const bf16x8*)(gl + px * 16 + q * 8) : zz;
      *(bf16x8*)&hbuf[s][px * 20 + q * 8] = vh;
      *(bf16x8*)&lbuf[s][px * 20 + q * 8] = vl;
    }
  };
  stage(0, 0);
  __syncthreads();
  for (int ky = 0; ky < 9; ++ky) {
    if (ky < 8) stage(ky + 1, (ky + 1) & 1);
    int s = ky & 1;
#pragma unroll
    for (int p = 0; p < 5; ++p) {
      const unsigned short* wt =
          wpk + ((size_t)(ky * 5 + p) * 8) * 512 + (size_t)l * 8;
      bf16x8 Bh[4], Bl[4];
#pragma unroll
      for (int nt = 0; nt < 4; ++nt) {
        Bh[nt] = *(const bf16x8*)(wt + (nt * 2 + 0) * 512);
        Bl[nt] = *(const bf16x8*)(wt + (nt * 2 + 1) * 512);
      }
#pragma unroll
      for (int mt = 0; mt < 2; ++mt) {
        int px = wbase + mt * 16 + lm + 2 * p + (lg >> 1);
        bf16x8 Ah = *(const bf16x8*)&hbuf[s][px * 20 + (lg & 1) * 8];
        bf16x8 Al = *(const bf16x8*)&lbuf[s][px * 20 + (lg & 1) * 8];
#pragma unroll
        for (int nt = 0; nt < 4; ++nt) {
          acc[mt][nt] =
              __builtin_amdgcn_mfma_f32_16x16x32_bf16(Ah, Bh[nt], acc[mt][nt], 0, 0, 0);
          acc[mt][nt] =
              __builtin_amdgcn_mfma_f32_16x16x32_bf16(Ah, Bl[nt], acc[mt][nt], 0, 0, 0);
          acc[mt][nt] =
              __builtin_amdgcn_mfma_f32_16x16x32_bf16(Al, Bh[nt], acc[mt][nt], 0, 0, 0);
        }
      }
    }
    __syncthreads();
  }
  float a = alpha[0];
#pragma unroll
  for (int mt = 0; mt < 2; ++mt)
#pragma unroll
    for (int nt = 0; nt < 4; ++nt)
#pragma unroll
      for (int r = 0; r < 4; ++r) {
        int px = wbase + mt * 16 + lg * 4 + r;
        int co = nt * 16 + lm;
        float v = acc[mt][nt][r] + bias[co];
        out[((size_t)(b * 128 + y) * 128 + px) * 64 + co] = v >= 0.f ? v : a * v;
      }
}

// ------- sr2: 1x1 conv 64->32, direct (no LDS), thread = 1 px, SGPR weights --------
__global__ __launch_bounds__(256) void k_sr2(
    const float* __restrict__ s1, const float* __restrict__ wt,
    const float* __restrict__ bias, const float* __restrict__ alpha,
    float* __restrict__ s2p) {
  int i = blockIdx.x * 256 + threadIdx.x;
  if (i >= 4 * 16384) return;
  int b = i >> 14, n = i & 16383, y = n >> 7, x = n & 127;
  const float* ip = s1 + (size_t)i * 64;
  float acc[32];
#pragma unroll
  for (int co = 0; co < 32; ++co) acc[co] = 0.f;
#pragma unroll
  for (int ci = 0; ci < 64; ci += 4) {
    float4 v = *(const float4*)(ip + ci);
#pragma unroll
    for (int c = 0; c < 4; ++c) {
      float vv = ((const float*)&v)[c];
      const float* wr = wt + (ci + c) * 32;
#pragma unroll
      for (int co = 0; co < 32; ++co) acc[co] += vv * wr[co];
    }
  }
  float a = alpha[0];
  float* op = s2p + ((size_t)(b * 132 + y + 2) * 132 + x + 2) * 32;
#pragma unroll
  for (int co = 0; co < 32; ++co) {
    float v = acc[co] + bias[co];
    op[co] = v >= 0.f ? v : a * v;
  }
}

// ------- sr3: 5x5 conv 32->1, direct (zero-padded input, L2-resident) --------------
__global__ __launch_bounds__(256) void k_sr3(
    const float* __restrict__ s2p, const float* __restrict__ wt,
    const float* __restrict__ bias, const float* __restrict__ alpha,
    float* __restrict__ out) {
  int i = blockIdx.x * 256 + threadIdx.x;
  if (i >= 4 * 16384) return;
  int b = i >> 14, n = i & 16383, y = n >> 7, x = n & 127;
  float acc = 0.f;
#pragma unroll
  for (int ky = 0; ky < 5; ++ky) {
#pragma unroll
    for (int kx = 0; kx < 5; ++kx) {
      const float* wr = wt + (ky * 5 + kx) * 32;
      const float* ip = s2p + ((size_t)(b * 132 + y + ky) * 132 + x + kx) * 32;
#pragma unroll
      for (int ci = 0; ci < 32; ci += 4) {
        float4 v = *(const float4*)(ip + ci);
        acc += v.x * wr[ci] + v.y * wr[ci + 1] + v.z * wr[ci + 2] + v.w * wr[ci + 3];
      }
    }
  }
  float a = alpha[0];
  float v = acc + bias[0];
  out[i] = v >= 0.f ? v : a * v;
}

// ====== GCN edge pipeline, LDS-privatized ======
template <int HALF>
__global__ __launch_bounds__(1024) void k_degp(
    const int* __restrict__ ei, const float* __restrict__ ew,
    float* __restrict__ pdeg, int* __restrict__ cnt, int* __restrict__ rank, int E) {
  __shared__ float degl[16384];
  for (int i = threadIdx.x; i < 16384; i += 1024) degl[i] = 0.f;
  __syncthreads();
  int chunk = (E + gridDim.x - 1) / gridDim.x;
  int base = blockIdx.x * chunk;
  int end = min(E, base + chunk);
  for (int e = base + (int)threadIdx.x; e < end; e += 1024) {
    int col = ei[E + e];
    float w = ew[e];
    if ((col >> 14) == HALF) atomicAdd(&degl[col & 16383], w);
    if (HALF == 1) {
      int row = ei[e];
      if (row < NS && col >= NS) rank[e] = atomicAdd(&cnt[col - NS], 1);
    }
  }
  __syncthreads();
  float* pd = pdeg + (size_t)blockIdx.x * 16384;
  for (int i = threadIdx.x; i < 16384; i += 1024) pd[i] = degl[i];
}

__global__ void k_dis2(const float* __restrict__ pdegA, const float* __restrict__ pdegB,
                       float* __restrict__ dis, int nb) {
  int n = blockIdx.x * 256 + threadIdx.x;
  if (n >= 2 * NS) return;
  const float* p = (n < NS ? pdegA : pdegB) + (n & 16383);
  float s = 1.0f;
  for (int b = 0; b < nb; ++b) s += p[(size_t)b * 16384];
  dis[n] = rsqrtf(s);
}

__global__ __launch_bounds__(1024) void k_scan(const int* __restrict__ cnt,
                                               int* __restrict__ ptr) {
  __shared__ int ps[1024];
  int tid = threadIdx.x;
  int base = tid * 16;
  int v[16];
  int s = 0;
#pragma unroll
  for (int k = 0; k < 16; ++k) {
    v[k] = s;
    s += cnt[base + k];
  }
  ps[tid] = s;
  __syncthreads();
  for (int off = 1; off < 1024; off <<= 1) {
    int t = (tid >= off) ? ps[tid - off] : 0;
    __syncthreads();
    ps[tid] += t;
    __syncthreads();
  }
  int chunkoff = (tid == 0) ? 0 : ps[tid - 1];
#pragma unroll
  for (int k = 0; k < 16; ++k) ptr[base + k] = chunkoff + v[k];
  if (tid == 1023) ptr[16384] = ps[1023];
}

__global__ void k_bucket2(const int* __restrict__ ei, const float* __restrict__ ew,
                          const float* __restrict__ dis, const int* __restrict__ ptr,
                          const int* __restrict__ rank, int* __restrict__ erow,
                          float* __restrict__ enrm, int E) {
  int e = blockIdx.x * 256 + threadIdx.x;
  if (e >= E) return;
  int row = ei[e], col = ei[E + e];
  if (row >= NS || col < NS) return;
  int cp = col - NS;
  int pos = ptr[cp] + rank[e];
  erow[pos] = row;
  enrm[pos] = dis[row] * ew[e] * dis[col];
}

// ----- gather -> imgp hi/lo bf16 planes (split moved here from convs staging) -------
__global__ __launch_bounds__(256) void k_gather(
    const int* __restrict__ ptr, const int* __restrict__ erow,
    const float* __restrict__ enrm, const float* __restrict__ xl,
    const float* __restrict__ gb, unsigned short* __restrict__ imgph,
    unsigned short* __restrict__ imgpl) {
  int cp = blockIdx.x * 4 + (threadIdx.x >> 6);
  int l = threadIdx.x & 63;
  int b = l >> 4, f = l & 15;
  bool act = f < 10;
  float acc = 0.f;
  int s = ptr[cp], e1 = ptr[cp + 1];
  for (int e = s; e < e1; ++e) {
    int row = erow[e];
    float nrm = enrm[e];
    if (act) acc += xl[((size_t)b * 16384 + row) * 10 + f] * nrm;
  }
  if (act) {
    int y = cp >> 7, x = cp & 127;
    float v = acc + gb[f];
    unsigned short h = bf16_rne(v);
    unsigned short lo = bf16_rne(v - __uint_as_float((unsigned)h << 16));
    size_t idx = ((size_t)(b * 136 + y + 4) * 136 + x + 4) * 16 + f;
    imgph[idx] = h;
    imgpl[idx] = lo;
  }
}

// ---------------- launcher ----------------
extern "C" void kernel_launch(void* const* d_in, const int* in_sizes, int n_in,
                              void* d_out, int out_size, void* d_ws, size_t ws_size,
                              hipStream_t stream) {
  const float* sino = (const float*)d_in[0];
  const int* ei = (const int*)d_in[1];
  const float* ew = (const float*)d_in[2];
  const float* w1 = (const float*)d_in[3];
  const float* w2 = (const float*)d_in[4];
  const float* w3 = (const float*)d_in[5];
  const float* w4 = (const float*)d_in[6];
  const float* w5 = (const float*)d_in[7];
  const float* gw = (const float*)d_in[8];
  const float* sw1 = (const float*)d_in[9];
  const float* sw2 = (const float*)d_in[10];
  const float* sw3 = (const float*)d_in[11];
  const float* b1 = (const float*)d_in[12];
  const float* b2 = (const float*)d_in[13];
  const float* b3 = (const float*)d_in[14];
  const float* b4 = (const float*)d_in[15];
  const float* b5 = (const float*)d_in[16];
  const float* sb1 = (const float*)d_in[17];
  const float* sb2 = (const float*)d_in[18];
  const float* sb3 = (const float*)d_in[19];
  const float* gb = (const float*)d_in[20];
  const float* bng = (const float*)d_in[21];
  const float* bnb = (const float*)d_in[22];
  const float* p1 = (const float*)d_in[23];
  const float* p2 = (const float*)d_in[24];
  const float* p3 = (const float*)d_in[25];
  const float* p4 = (const float*)d_in[26];
  const float* p5 = (const float*)d_in[27];
  const float* sp1 = (const float*)d_in[28];
  const float* sp2 = (const float*)d_in[29];
  const float* sp3 = (const float*)d_in[30];
  const int E = in_sizes[2];

  char* ws = (char*)d_ws;
  size_t off = 0;
  auto alloc = [&](size_t bytes) {
    char* p = ws + off;
    off += (bytes + 255) & ~(size_t)255;
    return p;
  };
  const size_t PL = (size_t)4 * 134 * 134 * 64;     // conv plane elements
  const size_t IPL = (size_t)4 * 136 * 136 * 16;    // imgp plane elements
  float* x1p = (float*)alloc(PL * 4);
  unsigned short* xh1 = (unsigned short*)alloc(PL * 2);
  unsigned short* xl1 = (unsigned short*)alloc(PL * 2);
  unsigned short* xh2 = (unsigned short*)alloc(PL * 2);
  unsigned short* xl2 = (unsigned short*)alloc(PL * 2);
  unsigned short* wpk2 = (unsigned short*)alloc(401408 * 2);
  unsigned short* wpk3 = (unsigned short*)alloc(401408 * 2);
  unsigned short* wpk4 = (unsigned short*)alloc(401408 * 2);
  unsigned short* wpk5 = (unsigned short*)alloc(100352 * 2);
  unsigned short* wpks1 = (unsigned short*)alloc(184320 * 2);
  float* wt1 = (float*)alloc(3136 * 4);
  float* wts2 = (float*)alloc(2048 * 4);
  float* wts3 = (float*)alloc(800 * 4);
  double* bnsum = (double*)alloc(128 * 8);
  float* bnsc = (float*)alloc(128 * 4);
  float* xl = (float*)alloc((size_t)4 * 16384 * 10 * 4);
  float* pdegA = (float*)alloc((size_t)64 * 16384 * 4);
  float* pdegB = (float*)alloc((size_t)64 * 16384 * 4);
  float* dis = (float*)alloc(32768 * 4);
  int* cnt = (int*)alloc(16384 * 4);
  int* ptr = (int*)alloc(16385 * 4);
  int* rank = (int*)alloc((size_t)E * 4);
  int* erow = (int*)alloc((size_t)E * 4);
  float* enrm = (float*)alloc((size_t)E * 4);
  unsigned short* imgph = (unsigned short*)alloc(IPL * 2);
  unsigned short* imgpl = (unsigned short*)alloc(IPL * 2);
  float* s1 = (float*)alloc((size_t)4 * 128 * 128 * 64 * 4);
  float* s2p = (float*)alloc((size_t)4 * 132 * 132 * 32 * 4);

  // zero plane halos / accumulators (bf16 zero == 0x0000)
  hipMemsetAsync(xh1, 0, PL * 2, stream);
  hipMemsetAsync(xl1, 0, PL * 2, stream);
  hipMemsetAsync(xh2, 0, PL * 2, stream);
  hipMemsetAsync(xl2, 0, PL * 2, stream);
  hipMemsetAsync(bnsum, 0, 128 * 8, stream);
  hipMemsetAsync(cnt, 0, 16384 * 4, stream);
  hipMemsetAsync(imgph, 0, IPL * 2, stream);
  hipMemsetAsync(imgpl, 0, IPL * 2, stream);
  hipMemsetAsync(s2p, 0, (size_t)4 * 132 * 132 * 32 * 4, stream);

  // weight prep
  k_wpack<<<784, 256, 0, stream>>>(w2, wpk2);
  k_wpack<<<784, 256, 0, stream>>>(w3, wpk3);
  k_wpack<<<784, 256, 0, stream>>>(w4, wpk4);
  k_wpack5<<<392, 256, 0, stream>>>(w5, wpk5);
  k_wpacks<<<720, 256, 0, stream>>>(sw1, wpks1);
  k_wtrans<<<13, 256, 0, stream>>>(w1, wt1, 64, 1, 1, 7);
  k_wtrans<<<8, 256, 0, stream>>>(sw2, wts2, 32, 64, 64, 1);
  k_wtrans<<<4, 256, 0, stream>>>(sw3, wts3, 1, 32, 32, 5);

  k_conv1<<<512, 128, 0, stream>>>(sino, wt1, b1, p1, x1p);
  k_bnstats<<<128, 256, 0, stream>>>(x1p, bnsum);
  k_bnfinal<<<1, 64, 0, stream>>>(bnsum, bnsc, bng, bnb);
  // BN on interior -> hi/lo planes (halo stays zero; ref zero-pads AFTER BN).
  k_bnapply<<<4096, 256, 0, stream>>>(x1p, bnsc, xh1, xl1);

  // MFMA split-bf16 convs on bf16-plane IO, XCD-swizzled, co-split waves (R17)
  k_convm<<<512, 256, 0, stream>>>(xh1, xl1, wpk2, b2, p2, xh2, xl2);
  k_convm<<<512, 256, 0, stream>>>(xh2, xl2, wpk3, b3, p3, xh1, xl1);
  k_convm<<<512, 256, 0, stream>>>(xh1, xl1, wpk4, b4, p4, xh2, xl2);
  // conv5 + GCN lin via MFMA
  k_convm5<<<512, 256, 0, stream>>>(xh2, xl2, wpk5, b5, p5, gw, xl);

  // edge pipeline: LDS-privatized deg partials + fused CSR rank (64 partials)
  k_degp<0><<<64, 1024, 0, stream>>>(ei, ew, pdegA, cnt, rank, E);
  k_degp<1><<<64, 1024, 0, stream>>>(ei, ew, pdegB, cnt, rank, E);
  k_dis2<<<128, 256, 0, stream>>>(pdegA, pdegB, dis, 64);
  k_scan<<<1, 1024, 0, stream>>>(cnt, ptr);
  k_bucket2<<<(E + 255) / 256, 256, 0, stream>>>(ei, ew, dis, ptr, rank, erow, enrm, E);
  k_gather<<<4096, 256, 0, stream>>>(ptr, erow, enrm, xl, gb, imgph, imgpl);

  // SRNET: sr1 MFMA (plane input), sr2/sr3 direct
  k_convs<<<512, 256, 0, stream>>>(imgph, imgpl, wpks1, sb1, sp1, s1);
  k_sr2<<<256, 256, 0, stream>>>(s1, wts2, sb2, sp2, s2p);
  k_sr3<<<256, 256, 0, stream>>>(s2p, wts3, sb3, sp3, (float*)d_out);
}